// Round 12
// baseline (2683.030 us; speedup 1.0000x reference)
//
#include <hip/hip_runtime.h>
#include <cstdint>
#include <cstddef>

#define DEV __device__ __forceinline__

namespace {

constexpr int kN = 784, kC = 768, kH = 12, kD = 64;
constexpr int kM = 6272, kOC = 2304, kBH = 96;
constexpr size_t SZ_QKV1 = (size_t)kBH * kN * kD;
constexpr double kEps   = 2.0e-3;        // activation-round dither (proven harmless)
constexpr double kEpsW  = 3.0e-5;        // weight-round dither
constexpr double kEpsX0 = 3.0e-5;        // x0 floor dither
constexpr long long kDS = 1024;          // np-f32 exp_sum ambiguity band
constexpr long long kEP = 128;           // np-f32 (p*factor) product ulp band

DEV int dot4i8(int a, int b, int c) {
#if __has_builtin(__builtin_amdgcn_sdot4)
  return __builtin_amdgcn_sdot4(a, b, c, false);
#else
  return c + (int)(signed char)(a & 0xff)        * (int)(signed char)(b & 0xff)
           + (int)(signed char)((a >> 8) & 0xff) * (int)(signed char)((b >> 8) & 0xff)
           + (int)(signed char)((a >> 16) & 0xff)* (int)(signed char)((b >> 16) & 0xff)
           + (a >> 24) * (b >> 24);
#endif
}

DEV double wave_max_d(double v) {
  for (int o = 32; o; o >>= 1) v = fmax(v, __shfl_xor(v, o));
  return v;
}
DEV int wave_max_i(int v) {
  for (int o = 32; o; o >>= 1) v = max(v, __shfl_xor(v, o));
  return v;
}

// ctl: [0] u64 dbl max|h| ; [8] int max|qk| ; [16] u64 dbl max|proj| ;
// [24] u64 dbl max|pv|
DEV double ctl_hmax(const char* c)  { return __longlong_as_double(*(const long long*)(c)); }
DEV int    ctl_qkmax(const char* c) { return *(const int*)(c + 8); }
DEV double ctl_pmax(const char* c)  { return __longlong_as_double(*(const long long*)(c + 16)); }
DEV double ctl_pvmax(const char* c) { return __longlong_as_double(*(const long long*)(c + 24)); }

DEV double get_s1(const char* c) { return ctl_hmax(c) / 127.0; }
DEV double get_sa(const char* c) {
  double s1 = get_s1(c);
  double amax = ((double)ctl_qkmax(c) * (s1 * s1)) * 0.125;
  return amax / 127.0;
}
DEV double get_c2(const char* c) { return get_s1(c) * 3.0517578125e-05; }
DEV double get_so(const char* c) { return (ctl_pvmax(c) * get_c2(c)) / 127.0; }

// shift-exp of int_softmax, exact integer form. xi <= 0, x0i < 0.
DEV int p_eval(int xi, int x0i) {
  int x2 = xi + (xi >> 1) - (xi >> 4);
  x2 = max(x2, 15 * x0i);
  int q = x2 / x0i;
  int rrem = x2 - x0i * q;
  int base = rrem - 2 * x0i;
  return (q <= 14) ? (base << (14 - q)) : (base >> 1);
}

// np-f32 ambiguity-midpointed P: average of floor((p*f +- kEP)/2^16) over f in {fLo,fHi}
DEV float p_final(long long p, long long fLo, long long fHi) {
  long long a = (p * fLo - kEP) >> 16;
  long long b = (p * fLo + kEP) >> 16;
  if (fLo == fHi) return 0.5f * (float)(a + b);
  long long c = (p * fHi - kEP) >> 16;
  long long d = (p * fHi + kEP) >> 16;
  return 0.25f * (float)(a + b + c + d);
}

// ---------------- weight quantization: shared scale, dithered A/B ints ----------------
__global__ __launch_bounds__(256) void k_quant_w(
    const float* __restrict__ Wq, const float* __restrict__ Wp,
    const float* __restrict__ s_in_p,
    int8_t* __restrict__ wq8A, int8_t* __restrict__ wq8B,
    int8_t* __restrict__ wp8A, int8_t* __restrict__ wp8B,
    double* __restrict__ outs_q, double* __restrict__ wsp) {
  int r = blockIdx.x;
  bool isq = r < kOC;
  const float* row = isq ? Wq + (size_t)r * kC : Wp + (size_t)(r - kOC) * kC;
  double m = 0.0;
  for (int i = threadIdx.x; i < kC; i += 256) m = fmax(m, fabs((double)row[i]));
  m = wave_max_d(m);
  __shared__ double sred[4];
  __shared__ double s_ws;
  if ((threadIdx.x & 63) == 0) sred[threadIdx.x >> 6] = m;
  __syncthreads();
  if (threadIdx.x == 0) {
    double mm = fmax(fmax(sred[0], sred[1]), fmax(sred[2], sred[3]));
    double ws = mm / 127.0;
    s_ws = ws;
    if (isq) outs_q[r] = ws * (double)s_in_p[0];
    else     wsp[r - kOC] = ws;
  }
  __syncthreads();
  double ws = s_ws;
  int8_t* dA = isq ? wq8A + (size_t)r * kC : wp8A + (size_t)(r - kOC) * kC;
  int8_t* dB = isq ? wq8B + (size_t)r * kC : wp8B + (size_t)(r - kOC) * kC;
  for (int i = threadIdx.x; i < kC; i += 256) {
    double arg = (double)row[i] / ws;
    dA[i] = (int8_t)(int)fmin(fmax(rint(arg - kEpsW), -128.0), 127.0);
    dB[i] = (int8_t)(int)fmin(fmax(rint(arg + kEpsW), -128.0), 127.0);
  }
}

// ---------------- x quantization (exact, shared) ----------------
__global__ __launch_bounds__(256) void k_quant_x(
    const float* __restrict__ x, const float* __restrict__ s_in_p,
    int8_t* __restrict__ x8) {
  double s = (double)s_in_p[0];
  int total = kM * kC;
  for (int i = blockIdx.x * 256 + threadIdx.x; i < total; i += gridDim.x * 256)
    x8[i] = (int8_t)(int)rint((double)x[i] / s);
}

// ---------------- fused GEMM1 per branch: MODE 0 hmax, MODE 1 quantize ----------------
template <int MODE>
__global__ __launch_bounds__(256) void k_gemm1q(
    const int8_t* __restrict__ A, const int8_t* __restrict__ Bm,
    const double* __restrict__ outs_q, char* __restrict__ ctl,
    int8_t* __restrict__ qkv8, double dit) {
  __shared__ int8_t As[64][80];
  __shared__ int8_t Bs[64][80];
  int bm = blockIdx.y * 64, bn = blockIdx.x * 64;
  int tid = threadIdx.x;
  int lr = tid >> 2, lc = (tid & 3) << 4;
  int tr = (tid >> 4) << 2, tc = (tid & 15) << 2;
  int acc[4][4] = {};
  for (int k0 = 0; k0 < kC; k0 += 64) {
    *(int4*)&As[lr][lc] = *(const int4*)&A[(size_t)(bm + lr) * kC + k0 + lc];
    *(int4*)&Bs[lr][lc] = *(const int4*)&Bm[(size_t)(bn + lr) * kC + k0 + lc];
    __syncthreads();
#pragma unroll
    for (int kk = 0; kk < 16; ++kk) {
      int a[4], b[4];
#pragma unroll
      for (int i = 0; i < 4; ++i) a[i] = *(const int*)&As[tr + i][kk << 2];
#pragma unroll
      for (int j = 0; j < 4; ++j) b[j] = *(const int*)&Bs[tc + j][kk << 2];
#pragma unroll
      for (int i = 0; i < 4; ++i)
#pragma unroll
        for (int j = 0; j < 4; ++j) acc[i][j] = dot4i8(a[i], b[j], acc[i][j]);
    }
    __syncthreads();
  }
  if (MODE == 0) {
    double m = 0.0;
#pragma unroll
    for (int i = 0; i < 4; ++i)
#pragma unroll
      for (int j = 0; j < 4; ++j)
        m = fmax(m, fabs((double)acc[i][j] * outs_q[bn + tc + j]));
    m = wave_max_d(m);
    __shared__ double sred[4];
    if ((tid & 63) == 0) sred[tid >> 6] = m;
    __syncthreads();
    if (tid == 0) {
      double mm = fmax(fmax(sred[0], sred[1]), fmax(sred[2], sred[3]));
      atomicMax((unsigned long long*)ctl,
                (unsigned long long)__double_as_longlong(mm));
    }
  } else {
    double s1 = get_s1(ctl);
#pragma unroll
    for (int i = 0; i < 4; ++i)
#pragma unroll
      for (int j = 0; j < 4; ++j) {
        int n = bm + tr + i, o = bn + tc + j;
        double arg = ((double)acc[i][j] * outs_q[o]) / s1;
        double v = fmin(fmax(rint(arg + dit), -128.0), 127.0);
        int which = o / kC, rem = o % kC;
        int hh = rem >> 6, dd = rem & 63;
        int bb = n / kN, nn = n % kN;
        qkv8[(size_t)which * SZ_QKV1 + (((size_t)bb * kH + hh) * kN + nn) * kD + dd] =
            (int8_t)(int)v;
      }
  }
}

// ---------------- proj int8 GEMM (exact) ----------------
__global__ __launch_bounds__(256) void k_gemm_i8(
    const int8_t* __restrict__ A, const int8_t* __restrict__ Bm,
    int* __restrict__ Cout, int Ncols, int K) {
  __shared__ int8_t As[64][80];
  __shared__ int8_t Bs[64][80];
  int bm = blockIdx.y * 64, bn = blockIdx.x * 64;
  int tid = threadIdx.x;
  int lr = tid >> 2, lc = (tid & 3) << 4;
  int tr = (tid >> 4) << 2, tc = (tid & 15) << 2;
  int acc[4][4] = {};
  for (int k0 = 0; k0 < K; k0 += 64) {
    *(int4*)&As[lr][lc] = *(const int4*)&A[(size_t)(bm + lr) * K + k0 + lc];
    *(int4*)&Bs[lr][lc] = *(const int4*)&Bm[(size_t)(bn + lr) * K + k0 + lc];
    __syncthreads();
#pragma unroll
    for (int kk = 0; kk < 16; ++kk) {
      int a[4], b[4];
#pragma unroll
      for (int i = 0; i < 4; ++i) a[i] = *(const int*)&As[tr + i][kk << 2];
#pragma unroll
      for (int j = 0; j < 4; ++j) b[j] = *(const int*)&Bs[tc + j][kk << 2];
#pragma unroll
      for (int i = 0; i < 4; ++i)
#pragma unroll
        for (int j = 0; j < 4; ++j) acc[i][j] = dot4i8(a[i], b[j], acc[i][j]);
    }
    __syncthreads();
  }
#pragma unroll
  for (int i = 0; i < 4; ++i)
#pragma unroll
    for (int j = 0; j < 4; ++j)
      Cout[(size_t)(bm + tr + i) * Ncols + (bn + tc + j)] = acc[i][j];
}

// ---------------- global max |q.k| (int exact; per branch, shared ctl) ----------------
__global__ __launch_bounds__(256) void k_qkmax(
    const int8_t* __restrict__ q8, const int8_t* __restrict__ k8,
    char* __restrict__ ctl) {
  __shared__ int8_t Qs[64][80];
  __shared__ int8_t Ks[64][80];
  int bh = blockIdx.z;
  int n0 = blockIdx.y * 64, m0 = blockIdx.x * 64;
  const int8_t* qb = q8 + (size_t)bh * kN * kD;
  const int8_t* kb = k8 + (size_t)bh * kN * kD;
  int tid = threadIdx.x;
  int lr = tid >> 2, lc = (tid & 3) << 4;
  int4 z4 = make_int4(0, 0, 0, 0);
  *(int4*)&Qs[lr][lc] = (n0 + lr < kN) ? *(const int4*)&qb[(size_t)(n0 + lr) * kD + lc] : z4;
  *(int4*)&Ks[lr][lc] = (m0 + lr < kN) ? *(const int4*)&kb[(size_t)(m0 + lr) * kD + lc] : z4;
  __syncthreads();
  int tr = (tid >> 4) << 2, tc = (tid & 15) << 2;
  int acc[4][4] = {};
#pragma unroll
  for (int kk = 0; kk < 16; ++kk) {
    int a[4], b[4];
#pragma unroll
    for (int i = 0; i < 4; ++i) a[i] = *(const int*)&Qs[tr + i][kk << 2];
#pragma unroll
    for (int j = 0; j < 4; ++j) b[j] = *(const int*)&Ks[tc + j][kk << 2];
#pragma unroll
    for (int i = 0; i < 4; ++i)
#pragma unroll
      for (int j = 0; j < 4; ++j) acc[i][j] = dot4i8(a[i], b[j], acc[i][j]);
  }
  int mx = 0;
#pragma unroll
  for (int i = 0; i < 4; ++i)
#pragma unroll
    for (int j = 0; j < 4; ++j) mx = max(mx, abs(acc[i][j]));
  mx = wave_max_i(mx);
  __shared__ int sred[4];
  if ((tid & 63) == 0) sred[tid >> 6] = mx;
  __syncthreads();
  if (tid == 0) {
    int mm = max(max(sred[0], sred[1]), max(sred[2], sred[3]));
    atomicMax((int*)(ctl + 8), mm);
  }
}

// --- fused attn per branch: qk -> quant(dither) -> int_softmax(factor-midpoint) -> PV ---
__global__ __launch_bounds__(256) void k_attn(
    const int8_t* __restrict__ q8, const int8_t* __restrict__ k8,
    const int8_t* __restrict__ v8, char* __restrict__ ctl,
    float* __restrict__ pv, double dit, double x0dit) {
  double s1 = get_s1(ctl);
  double s1s1 = s1 * s1;
  double s_a = get_sa(ctl);
  double x0 = floor(-1.0 / s_a + x0dit);

  int bh = blockIdx.y;
  int n0 = blockIdx.x * 16;
  int bb = bh / kH, hh = bh % kH;
  const int8_t* qb = q8 + ((size_t)bh * kN + n0) * kD;
  const int8_t* kb = k8 + (size_t)bh * kN * kD;
  const int8_t* vb = v8 + (size_t)bh * kN * kD;

  __shared__ int8_t Qs[16][64];
  __shared__ int8_t KVs[64][80];
  __shared__ int8_t AQ[16][832];
  __shared__ float  P[16][832];

  int tid = threadIdx.x;
  ((int*)Qs)[tid] = ((const int*)qb)[tid];

  int lr = tid >> 2, lc = (tid & 3) << 4;
  int4 z4 = make_int4(0, 0, 0, 0);

  // phase 1: scores -> quantized attn ints (dithered round)
  {
    int r = tid >> 4;
    int mb = tid & 15;
    for (int mt = 0; mt < 13; ++mt) {
      int m0 = mt * 64;
      __syncthreads();
      *(int4*)&KVs[lr][lc] =
          (m0 + lr < kN) ? *(const int4*)&kb[(size_t)(m0 + lr) * kD + lc] : z4;
      __syncthreads();
#pragma unroll
      for (int j = 0; j < 4; ++j) {
        int m = mb + j * 16;
        int acc = 0;
#pragma unroll
        for (int kk = 0; kk < 16; ++kk)
          acc = dot4i8(*(const int*)&Qs[r][kk << 2], *(const int*)&KVs[m][kk << 2], acc);
        double attnv = ((double)acc * s1s1) * 0.125;
        double aq = fmin(fmax(rint(attnv / s_a + dit), -128.0), 127.0);
        AQ[r][m0 + m] = (int8_t)(int)aq;
      }
    }
  }
  __syncthreads();

  // phase 2: integer int_softmax with np-f32 factor/product ambiguity midpoint
  {
    int x0i = (int)x0;
    int wid = tid >> 6, lane = tid & 63;
    for (int rr = 0; rr < 4; ++rr) {
      int r = wid * 4 + rr;
      int rmax = -128;
      for (int m = lane; m < kN; m += 64) rmax = max(rmax, (int)AQ[r][m]);
      rmax = wave_max_i(rmax);
      long long sd = 0;
      for (int m = lane; m < kN; m += 64)
        sd += p_eval((int)AQ[r][m] - rmax, x0i);
      for (int off = 32; off; off >>= 1) sd += __shfl_xor(sd, off);
      long long S = sd > 2147483647LL ? 2147483647LL : sd;
      // np-f32 cannot hold S (> 2^24) exactly: factor is ambiguous within +-kDS
      long long SLo = S + kDS;
      long long SHi = S - kDS; if (SHi < 1) SHi = 1;
      if (SLo > 2147483647LL) SLo = 2147483647LL;
      long long fLo = 2147483647LL / SLo;   // smaller factor
      long long fHi = 2147483647LL / SHi;   // larger factor
      for (int m = lane; m < kN; m += 64)
        P[r][m] = p_final(p_eval((int)AQ[r][m] - rmax, x0i), fLo, fHi);
      for (int m = kN + lane; m < 832; m += 64) P[r][m] = 0.0f;
    }
  }

  // phase 3: PV in f64 (P is quarter-granular)
  double acc[4] = {0.0, 0.0, 0.0, 0.0};
  int r3 = tid >> 4, d0 = (tid & 15) << 2;
  for (int mt = 0; mt < 13; ++mt) {
    int m0 = mt * 64;
    __syncthreads();
    *(int4*)&KVs[lr][lc] =
        (m0 + lr < kN) ? *(const int4*)&vb[(size_t)(m0 + lr) * kD + lc] : z4;
    __syncthreads();
#pragma unroll
    for (int mm = 0; mm < 64; ++mm) {
      double p = (double)P[r3][m0 + mm];
      char4 v4 = *(const char4*)&KVs[mm][d0];
      acc[0] += p * (double)v4.x;
      acc[1] += p * (double)v4.y;
      acc[2] += p * (double)v4.z;
      acc[3] += p * (double)v4.w;
    }
  }
  double mymax = 0.0;
  size_t obase = ((size_t)bb * kN + (n0 + r3)) * kC + hh * kD + d0;
#pragma unroll
  for (int j = 0; j < 4; ++j) {
    pv[obase + j] = (float)acc[j];
    mymax = fmax(mymax, fabs(acc[j]));
  }
  mymax = wave_max_d(mymax);
  __shared__ double sredd[4];
  if ((tid & 63) == 0) sredd[tid >> 6] = mymax;
  __syncthreads();
  if (tid == 0) {
    double mm = fmax(fmax(sredd[0], sredd[1]), fmax(sredd[2], sredd[3]));
    atomicMax((unsigned long long*)(ctl + 24),
              (unsigned long long)__double_as_longlong(mm));
  }
}

// ---------------- quantize attn output per branch (dithered) ----------------
__global__ __launch_bounds__(256) void k_quant_o(
    const float* __restrict__ pv, const char* __restrict__ ctl,
    int8_t* __restrict__ o8, double dit) {
  double c2 = get_c2(ctl);
  double s_o = get_so(ctl);
  int total = kM * kC;
  for (int i = blockIdx.x * 256 + threadIdx.x; i < total; i += gridDim.x * 256) {
    double arg = ((double)pv[i] * c2) / s_o;
    double v = fmin(fmax(rint(arg + dit), -128.0), 127.0);
    o8[i] = (int8_t)(int)v;
  }
}

// ---------------- proj bias + max per branch (shared pmax atomic) ----------------
__global__ __launch_bounds__(256) void k_bias_max(
    int* __restrict__ p2, const double* __restrict__ wsp,
    const float* __restrict__ bias, char* __restrict__ ctl, double dit) {
  double s_o = get_so(ctl);
  int n = blockIdx.x;
  int* rowp = p2 + (size_t)n * kC;
  double m = 0.0;
  for (int o = threadIdx.x; o < kC; o += 256) {
    double outs = wsp[o] * s_o;
    double bint = rint((double)bias[o] / outs + dit);
    int a = rowp[o] + (int)bint;
    rowp[o] = a;
    m = fmax(m, fabs((double)a * outs));
  }
  m = wave_max_d(m);
  __shared__ double sred[4];
  if ((threadIdx.x & 63) == 0) sred[threadIdx.x >> 6] = m;
  __syncthreads();
  if (threadIdx.x == 0) {
    double mm = fmax(fmax(sred[0], sred[1]), fmax(sred[2], sred[3]));
    atomicMax((unsigned long long*)(ctl + 16),
              (unsigned long long)__double_as_longlong(mm));
  }
}

// ---------------- final: branch midpoint ----------------
__global__ __launch_bounds__(256) void k_final(
    const int* __restrict__ p2A, const int* __restrict__ p2B,
    const double* __restrict__ wsp,
    const char* __restrict__ ctl, float* __restrict__ out) {
  double s_o = get_so(ctl);
  double s_out = ctl_pmax(ctl) / 32767.0;
  int total = kM * kC;
  for (int i = blockIdx.x * 256 + threadIdx.x; i < total; i += gridDim.x * 256) {
    int o = i % kC;
    double outs = wsp[o] * s_o;
    double vA = fmin(fmax(rint(((double)p2A[i] * outs) / s_out - kEps), -32768.0), 32767.0);
    double vB = fmin(fmax(rint(((double)p2B[i] * outs) / s_out + kEps), -32768.0), 32767.0);
    out[i] = (float)(0.5 * (vA + vB) * s_out);
  }
  if (blockIdx.x == 0 && threadIdx.x == 0) out[total] = (float)s_out;
}

}  // namespace

extern "C" void kernel_launch(void* const* d_in, const int* in_sizes, int n_in,
                              void* d_out, int out_size, void* d_ws, size_t ws_size,
                              hipStream_t stream) {
  const float* x   = (const float*)d_in[0];
  const float* sin = (const float*)d_in[1];
  const float* Wq  = (const float*)d_in[2];
  const float* Wp  = (const float*)d_in[3];
  const float* bp  = (const float*)d_in[4];
  float* out = (float*)d_out;

  char* ws = (char*)d_ws;
  char* ctl = ws;
  size_t off = 1024;
  int8_t* x8   = (int8_t*)(ws + off); off += (size_t)kM * kC;
  int8_t* wq8A = (int8_t*)(ws + off); off += (size_t)kOC * kC;
  int8_t* wq8B = (int8_t*)(ws + off); off += (size_t)kOC * kC;
  int8_t* wp8A = (int8_t*)(ws + off); off += (size_t)kC * kC;
  int8_t* wp8B = (int8_t*)(ws + off); off += (size_t)kC * kC;
  off = (off + 255) & ~(size_t)255;
  double* outs_q = (double*)(ws + off); off += (size_t)kOC * 8;
  double* wsp    = (double*)(ws + off); off += (size_t)kC * 8;
  off = (off + 255) & ~(size_t)255;
  int8_t* qkvA = (int8_t*)(ws + off); off += 3 * SZ_QKV1;
  int8_t* qkvB = (int8_t*)(ws + off); off += 3 * SZ_QKV1;
  int8_t* qA = qkvA, *kA = qkvA + SZ_QKV1, *vA = qkvA + 2 * SZ_QKV1;
  int8_t* qB = qkvB, *kB = qkvB + SZ_QKV1, *vB = qkvB + 2 * SZ_QKV1;
  int8_t* o8A = (int8_t*)(ws + off); off += (size_t)kM * kC;
  int8_t* o8B = (int8_t*)(ws + off); off += (size_t)kM * kC;
  off = (off + 255) & ~(size_t)255;
  // pv dead after quant_o; p2 overlays pv (stream-ordered).
  float* pvA = (float*)(ws + off); int* p2A = (int*)pvA; off += (size_t)kM * kC * 4;
  float* pvB = (float*)(ws + off); int* p2B = (int*)pvB; off += (size_t)kM * kC * 4;

  dim3 g1(kOC / 64, kM / 64);
  hipMemsetAsync(ctl, 0, 1024, stream);
  k_quant_w<<<kOC + kC, 256, 0, stream>>>(Wq, Wp, sin, wq8A, wq8B, wp8A, wp8B,
                                          outs_q, wsp);
  k_quant_x<<<2048, 256, 0, stream>>>(x, sin, x8);
  k_gemm1q<0><<<g1, 256, 0, stream>>>(x8, wq8A, outs_q, ctl, nullptr, 0.0);
  k_gemm1q<0><<<g1, 256, 0, stream>>>(x8, wq8B, outs_q, ctl, nullptr, 0.0);
  k_gemm1q<1><<<g1, 256, 0, stream>>>(x8, wq8A, outs_q, ctl, qkvA, -kEps);
  k_gemm1q<1><<<g1, 256, 0, stream>>>(x8, wq8B, outs_q, ctl, qkvB, +kEps);
  k_qkmax<<<dim3(13, 13, kBH), 256, 0, stream>>>(qA, kA, ctl);
  k_qkmax<<<dim3(13, 13, kBH), 256, 0, stream>>>(qB, kB, ctl);
  k_attn<<<dim3(49, kBH), 256, 0, stream>>>(qA, kA, vA, ctl, pvA, -kEps, -kEpsX0);
  k_attn<<<dim3(49, kBH), 256, 0, stream>>>(qB, kB, vB, ctl, pvB, +kEps, +kEpsX0);
  k_quant_o<<<2048, 256, 0, stream>>>(pvA, ctl, o8A, -kEps);
  k_quant_o<<<2048, 256, 0, stream>>>(pvB, ctl, o8B, +kEps);
  k_gemm_i8<<<dim3(kC / 64, kM / 64), 256, 0, stream>>>(o8A, wp8A, p2A, kC, kC);
  k_gemm_i8<<<dim3(kC / 64, kM / 64), 256, 0, stream>>>(o8B, wp8B, p2B, kC, kC);
  k_bias_max<<<kM, 256, 0, stream>>>(p2A, wsp, bp, ctl, -kEps);
  k_bias_max<<<kM, 256, 0, stream>>>(p2B, wsp, bp, ctl, +kEps);
  k_final<<<2048, 256, 0, stream>>>(p2A, p2B, wsp, ctl, out);
}

// Round 13
// 2178.969 us; speedup vs baseline: 1.2313x; 1.2313x over previous
//
#include <hip/hip_runtime.h>
#include <cstdint>
#include <cstddef>

#define DEV __device__ __forceinline__

namespace {

constexpr int kN = 784, kC = 768, kH = 12, kD = 64;
constexpr int kM = 6272, kOC = 2304, kBH = 96;
constexpr size_t SZ_QKV1 = (size_t)kBH * kN * kD;
constexpr double kEps   = 2.0e-3;        // activation-round dither
constexpr double kEpsW  = 3.0e-5;        // weight-round dither
constexpr double kEpsX0 = 3.0e-5;        // x0 floor dither
constexpr long long kDS = 1024;          // np-f32 exp_sum ambiguity band
constexpr long long kEP = 128;           // np-f32 (p*factor) product ulp band

DEV int dot4i8(int a, int b, int c) {
#if __has_builtin(__builtin_amdgcn_sdot4)
  return __builtin_amdgcn_sdot4(a, b, c, false);
#else
  return c + (int)(signed char)(a & 0xff)        * (int)(signed char)(b & 0xff)
           + (int)(signed char)((a >> 8) & 0xff) * (int)(signed char)((b >> 8) & 0xff)
           + (int)(signed char)((a >> 16) & 0xff)* (int)(signed char)((b >> 16) & 0xff)
           + (a >> 24) * (b >> 24);
#endif
}

DEV double wave_max_d(double v) {
  for (int o = 32; o; o >>= 1) v = fmax(v, __shfl_xor(v, o));
  return v;
}
DEV int wave_max_i(int v) {
  for (int o = 32; o; o >>= 1) v = max(v, __shfl_xor(v, o));
  return v;
}

// ctl: [0] u64 dbl max|h| ; [8] int max|qk| ; [16] u64 dbl max|proj| ;
// [24] u64 dbl max|pv|
DEV double ctl_hmax(const char* c)  { return __longlong_as_double(*(const long long*)(c)); }
DEV int    ctl_qkmax(const char* c) { return *(const int*)(c + 8); }
DEV double ctl_pmax(const char* c)  { return __longlong_as_double(*(const long long*)(c + 16)); }
DEV double ctl_pvmax(const char* c) { return __longlong_as_double(*(const long long*)(c + 24)); }

DEV double get_s1(const char* c) { return ctl_hmax(c) / 127.0; }
DEV double get_sa(const char* c) {
  double s1 = get_s1(c);
  double amax = ((double)ctl_qkmax(c) * (s1 * s1)) * 0.125;
  return amax / 127.0;
}
DEV double get_c2(const char* c) { return get_s1(c) * 3.0517578125e-05; }
DEV double get_so(const char* c) { return (ctl_pvmax(c) * get_c2(c)) / 127.0; }

// shift-exp of int_softmax, exact integer form. xi <= 0, x0i < 0.
DEV int p_eval(int xi, int x0i) {
  int x2 = xi + (xi >> 1) - (xi >> 4);
  x2 = max(x2, 15 * x0i);
  int q = x2 / x0i;
  int rrem = x2 - x0i * q;
  int base = rrem - 2 * x0i;
  return (q <= 14) ? (base << (14 - q)) : (base >> 1);
}

// Integer 4*P version of r12's p_final — bit-identical values (incl. p=0 -> -2).
DEV int p4_final(long long p, long long fLo, long long fHi) {
  long long a = (p * fLo - kEP) >> 16;
  long long b = (p * fLo + kEP) >> 16;
  if (fLo == fHi) return (int)((a + b) << 1);
  long long c = (p * fHi - kEP) >> 16;
  long long d = (p * fHi + kEP) >> 16;
  return (int)(a + b + c + d);
}

// ---------------- weight quantization: shared scale, dithered A/B ints ----------------
__global__ __launch_bounds__(256) void k_quant_w(
    const float* __restrict__ Wq, const float* __restrict__ Wp,
    const float* __restrict__ s_in_p,
    int8_t* __restrict__ wq8A, int8_t* __restrict__ wq8B,
    int8_t* __restrict__ wp8A, int8_t* __restrict__ wp8B,
    double* __restrict__ outs_q, double* __restrict__ wsp) {
  int r = blockIdx.x;
  bool isq = r < kOC;
  const float* row = isq ? Wq + (size_t)r * kC : Wp + (size_t)(r - kOC) * kC;
  double m = 0.0;
  for (int i = threadIdx.x; i < kC; i += 256) m = fmax(m, fabs((double)row[i]));
  m = wave_max_d(m);
  __shared__ double sred[4];
  __shared__ double s_ws;
  if ((threadIdx.x & 63) == 0) sred[threadIdx.x >> 6] = m;
  __syncthreads();
  if (threadIdx.x == 0) {
    double mm = fmax(fmax(sred[0], sred[1]), fmax(sred[2], sred[3]));
    double ws = mm / 127.0;
    s_ws = ws;
    if (isq) outs_q[r] = ws * (double)s_in_p[0];
    else     wsp[r - kOC] = ws;
  }
  __syncthreads();
  double ws = s_ws;
  int8_t* dA = isq ? wq8A + (size_t)r * kC : wp8A + (size_t)(r - kOC) * kC;
  int8_t* dB = isq ? wq8B + (size_t)r * kC : wp8B + (size_t)(r - kOC) * kC;
  for (int i = threadIdx.x; i < kC; i += 256) {
    double arg = (double)row[i] / ws;
    dA[i] = (int8_t)(int)fmin(fmax(rint(arg - kEpsW), -128.0), 127.0);
    dB[i] = (int8_t)(int)fmin(fmax(rint(arg + kEpsW), -128.0), 127.0);
  }
}

// ---------------- x quantization (exact, shared) ----------------
__global__ __launch_bounds__(256) void k_quant_x(
    const float* __restrict__ x, const float* __restrict__ s_in_p,
    int8_t* __restrict__ x8) {
  double s = (double)s_in_p[0];
  int total = kM * kC;
  for (int i = blockIdx.x * 256 + threadIdx.x; i < total; i += gridDim.x * 256)
    x8[i] = (int8_t)(int)rint((double)x[i] / s);
}

// ---------------- fused GEMM1 per branch: MODE 0 hmax, MODE 1 quantize ----------------
template <int MODE>
__global__ __launch_bounds__(256) void k_gemm1q(
    const int8_t* __restrict__ A, const int8_t* __restrict__ Bm,
    const double* __restrict__ outs_q, char* __restrict__ ctl,
    int8_t* __restrict__ qkv8, double dit) {
  __shared__ int8_t As[64][80];
  __shared__ int8_t Bs[64][80];
  int bm = blockIdx.y * 64, bn = blockIdx.x * 64;
  int tid = threadIdx.x;
  int lr = tid >> 2, lc = (tid & 3) << 4;
  int tr = (tid >> 4) << 2, tc = (tid & 15) << 2;
  int acc[4][4] = {};
  for (int k0 = 0; k0 < kC; k0 += 64) {
    *(int4*)&As[lr][lc] = *(const int4*)&A[(size_t)(bm + lr) * kC + k0 + lc];
    *(int4*)&Bs[lr][lc] = *(const int4*)&Bm[(size_t)(bn + lr) * kC + k0 + lc];
    __syncthreads();
#pragma unroll
    for (int kk = 0; kk < 16; ++kk) {
      int a[4], b[4];
#pragma unroll
      for (int i = 0; i < 4; ++i) a[i] = *(const int*)&As[tr + i][kk << 2];
#pragma unroll
      for (int j = 0; j < 4; ++j) b[j] = *(const int*)&Bs[tc + j][kk << 2];
#pragma unroll
      for (int i = 0; i < 4; ++i)
#pragma unroll
        for (int j = 0; j < 4; ++j) acc[i][j] = dot4i8(a[i], b[j], acc[i][j]);
    }
    __syncthreads();
  }
  if (MODE == 0) {
    double m = 0.0;
#pragma unroll
    for (int i = 0; i < 4; ++i)
#pragma unroll
      for (int j = 0; j < 4; ++j)
        m = fmax(m, fabs((double)acc[i][j] * outs_q[bn + tc + j]));
    m = wave_max_d(m);
    __shared__ double sred[4];
    if ((tid & 63) == 0) sred[tid >> 6] = m;
    __syncthreads();
    if (tid == 0) {
      double mm = fmax(fmax(sred[0], sred[1]), fmax(sred[2], sred[3]));
      atomicMax((unsigned long long*)ctl,
                (unsigned long long)__double_as_longlong(mm));
    }
  } else {
    double s1 = get_s1(ctl);
#pragma unroll
    for (int i = 0; i < 4; ++i)
#pragma unroll
      for (int j = 0; j < 4; ++j) {
        int n = bm + tr + i, o = bn + tc + j;
        double arg = ((double)acc[i][j] * outs_q[o]) / s1;
        double v = fmin(fmax(rint(arg + dit), -128.0), 127.0);
        int which = o / kC, rem = o % kC;
        int hh = rem >> 6, dd = rem & 63;
        int bb = n / kN, nn = n % kN;
        qkv8[(size_t)which * SZ_QKV1 + (((size_t)bb * kH + hh) * kN + nn) * kD + dd] =
            (int8_t)(int)v;
      }
  }
}

// ---------------- proj int8 GEMM (exact) ----------------
__global__ __launch_bounds__(256) void k_gemm_i8(
    const int8_t* __restrict__ A, const int8_t* __restrict__ Bm,
    int* __restrict__ Cout, int Ncols, int K) {
  __shared__ int8_t As[64][80];
  __shared__ int8_t Bs[64][80];
  int bm = blockIdx.y * 64, bn = blockIdx.x * 64;
  int tid = threadIdx.x;
  int lr = tid >> 2, lc = (tid & 3) << 4;
  int tr = (tid >> 4) << 2, tc = (tid & 15) << 2;
  int acc[4][4] = {};
  for (int k0 = 0; k0 < K; k0 += 64) {
    *(int4*)&As[lr][lc] = *(const int4*)&A[(size_t)(bm + lr) * K + k0 + lc];
    *(int4*)&Bs[lr][lc] = *(const int4*)&Bm[(size_t)(bn + lr) * K + k0 + lc];
    __syncthreads();
#pragma unroll
    for (int kk = 0; kk < 16; ++kk) {
      int a[4], b[4];
#pragma unroll
      for (int i = 0; i < 4; ++i) a[i] = *(const int*)&As[tr + i][kk << 2];
#pragma unroll
      for (int j = 0; j < 4; ++j) b[j] = *(const int*)&Bs[tc + j][kk << 2];
#pragma unroll
      for (int i = 0; i < 4; ++i)
#pragma unroll
        for (int j = 0; j < 4; ++j) acc[i][j] = dot4i8(a[i], b[j], acc[i][j]);
    }
    __syncthreads();
  }
#pragma unroll
  for (int i = 0; i < 4; ++i)
#pragma unroll
    for (int j = 0; j < 4; ++j)
      Cout[(size_t)(bm + tr + i) * Ncols + (bn + tc + j)] = acc[i][j];
}

// ---------------- global max |q.k| (int exact; per branch, shared ctl) ----------------
__global__ __launch_bounds__(256) void k_qkmax(
    const int8_t* __restrict__ q8, const int8_t* __restrict__ k8,
    char* __restrict__ ctl) {
  __shared__ int8_t Qs[64][80];
  __shared__ int8_t Ks[64][80];
  int bh = blockIdx.z;
  int n0 = blockIdx.y * 64, m0 = blockIdx.x * 64;
  const int8_t* qb = q8 + (size_t)bh * kN * kD;
  const int8_t* kb = k8 + (size_t)bh * kN * kD;
  int tid = threadIdx.x;
  int lr = tid >> 2, lc = (tid & 3) << 4;
  int4 z4 = make_int4(0, 0, 0, 0);
  *(int4*)&Qs[lr][lc] = (n0 + lr < kN) ? *(const int4*)&qb[(size_t)(n0 + lr) * kD + lc] : z4;
  *(int4*)&Ks[lr][lc] = (m0 + lr < kN) ? *(const int4*)&kb[(size_t)(m0 + lr) * kD + lc] : z4;
  __syncthreads();
  int tr = (tid >> 4) << 2, tc = (tid & 15) << 2;
  int acc[4][4] = {};
#pragma unroll
  for (int kk = 0; kk < 16; ++kk) {
    int a[4], b[4];
#pragma unroll
    for (int i = 0; i < 4; ++i) a[i] = *(const int*)&Qs[tr + i][kk << 2];
#pragma unroll
    for (int j = 0; j < 4; ++j) b[j] = *(const int*)&Ks[tc + j][kk << 2];
#pragma unroll
    for (int i = 0; i < 4; ++i)
#pragma unroll
      for (int j = 0; j < 4; ++j) acc[i][j] = dot4i8(a[i], b[j], acc[i][j]);
  }
  int mx = 0;
#pragma unroll
  for (int i = 0; i < 4; ++i)
#pragma unroll
    for (int j = 0; j < 4; ++j) mx = max(mx, abs(acc[i][j]));
  mx = wave_max_i(mx);
  __shared__ int sred[4];
  if ((tid & 63) == 0) sred[tid >> 6] = mx;
  __syncthreads();
  if (tid == 0) {
    int mm = max(max(sred[0], sred[1]), max(sred[2], sred[3]));
    atomicMax((int*)(ctl + 8), mm);
  }
}

// --- fused attn per branch (QBLK=8, Q in regs, int PV): bit-identical to r12 ---
__global__ __launch_bounds__(256) void k_attn(
    const int8_t* __restrict__ q8, const int8_t* __restrict__ k8,
    const int8_t* __restrict__ v8, char* __restrict__ ctl,
    float* __restrict__ pv, double dit, double x0dit) {
  double s1 = get_s1(ctl);
  double s1s1 = s1 * s1;
  double s_a = get_sa(ctl);
  double x0 = floor(-1.0 / s_a + x0dit);

  int bh = blockIdx.y;
  int n0 = blockIdx.x * 8;
  int bb = bh / kH, hh = bh % kH;
  const int8_t* kb = k8 + (size_t)bh * kN * kD;
  const int8_t* vb = v8 + (size_t)bh * kN * kD;

  __shared__ __align__(16) int8_t KVs[64][80];
  __shared__ int8_t AQ[8][832];
  __shared__ __align__(16) int    P4[8][832];

  int tid = threadIdx.x;
  int lr = tid >> 2, lc = (tid & 3) << 4;
  int4 z4 = make_int4(0, 0, 0, 0);

  // Q row for this thread's phase-1 role, in registers
  int qreg[16];
  {
    const int* qrow = (const int*)(q8 + ((size_t)bh * kN + n0 + (tid & 7)) * kD);
#pragma unroll
    for (int t = 0; t < 16; ++t) qreg[t] = qrow[t];
  }

  // phase 1: scores -> quantized attn ints (identical f64 expression to r12)
  {
    int r1 = tid & 7, mb1 = tid >> 3;
    for (int mt = 0; mt < 13; ++mt) {
      int m0 = mt * 64;
      __syncthreads();
      *(int4*)&KVs[lr][lc] =
          (m0 + lr < kN) ? *(const int4*)&kb[(size_t)(m0 + lr) * kD + lc] : z4;
      __syncthreads();
#pragma unroll
      for (int j = 0; j < 2; ++j) {
        int m = mb1 + (j << 5);
        int acc = 0;
#pragma unroll
        for (int kk = 0; kk < 16; ++kk)
          acc = dot4i8(qreg[kk], *(const int*)&KVs[m][kk << 2], acc);
        double attnv = ((double)acc * s1s1) * 0.125;
        double aq = fmin(fmax(rint(attnv / s_a + dit), -128.0), 127.0);
        AQ[r1][m0 + m] = (int8_t)(int)aq;
      }
    }
  }
  __syncthreads();

  // phase 2: integer int_softmax with factor/product ambiguity midpoint (x4 int)
  {
    int x0i = (int)x0;
    int wid = tid >> 6, lane = tid & 63;
    for (int rr = 0; rr < 2; ++rr) {
      int row = wid * 2 + rr;
      int rmax = -128;
      for (int m = lane; m < kN; m += 64) rmax = max(rmax, (int)AQ[row][m]);
      rmax = wave_max_i(rmax);
      long long sd = 0;
      for (int m = lane; m < kN; m += 64) {
        int p = p_eval((int)AQ[row][m] - rmax, x0i);
        P4[row][m] = p;
        sd += p;
      }
      for (int off = 32; off; off >>= 1) sd += __shfl_xor(sd, off);
      long long S = sd > 2147483647LL ? 2147483647LL : sd;
      long long SLo = S + kDS;
      long long SHi = S - kDS; if (SHi < 1) SHi = 1;
      if (SLo > 2147483647LL) SLo = 2147483647LL;
      long long fLo = 2147483647LL / SLo;
      long long fHi = 2147483647LL / SHi;
      for (int m = lane; m < kN; m += 64)
        P4[row][m] = p4_final((long long)P4[row][m], fLo, fHi);
      for (int m = kN + lane; m < 832; m += 64) P4[row][m] = 0;
    }
  }

  // phase 3: integer PV (exact; 0.25*acc64 == r12's f64 accumulation)
  int r3 = tid >> 5, d0 = (tid & 31) << 1;
  long long a64x = 0, a64y = 0;
  for (int mt = 0; mt < 13; ++mt) {
    int m0 = mt * 64;
    __syncthreads();
    *(int4*)&KVs[lr][lc] =
        (m0 + lr < kN) ? *(const int4*)&vb[(size_t)(m0 + lr) * kD + lc] : z4;
    __syncthreads();
    int ax = 0, ay = 0;
#pragma unroll
    for (int m4 = 0; m4 < 16; ++m4) {
      int4 p4v = *(const int4*)&P4[r3][m0 + (m4 << 2)];
      int pp[4] = {p4v.x, p4v.y, p4v.z, p4v.w};
#pragma unroll
      for (int e = 0; e < 4; ++e) {
        int mm = (m4 << 2) + e;
        short sv = *(const short*)&KVs[mm][d0];
        int vx = (int)(int8_t)(sv & 0xff);
        int vy = ((int)sv) >> 8;
        ax += __mul24(pp[e], vx);
        ay += __mul24(pp[e], vy);
      }
    }
    a64x += ax; a64y += ay;
  }
  double v0 = 0.25 * (double)a64x;
  double v1 = 0.25 * (double)a64y;
  size_t obase = ((size_t)bb * kN + (n0 + r3)) * kC + hh * kD + d0;
  pv[obase] = (float)v0;
  pv[obase + 1] = (float)v1;
  double mymax = fmax(fabs(v0), fabs(v1));
  mymax = wave_max_d(mymax);
  __shared__ double sredd[4];
  if ((tid & 63) == 0) sredd[tid >> 6] = mymax;
  __syncthreads();
  if (tid == 0) {
    double mm = fmax(fmax(sredd[0], sredd[1]), fmax(sredd[2], sredd[3]));
    atomicMax((unsigned long long*)(ctl + 24),
              (unsigned long long)__double_as_longlong(mm));
  }
}

// ---------------- quantize attn output per branch (dithered) ----------------
__global__ __launch_bounds__(256) void k_quant_o(
    const float* __restrict__ pv, const char* __restrict__ ctl,
    int8_t* __restrict__ o8, double dit) {
  double c2 = get_c2(ctl);
  double s_o = get_so(ctl);
  int total = kM * kC;
  for (int i = blockIdx.x * 256 + threadIdx.x; i < total; i += gridDim.x * 256) {
    double arg = ((double)pv[i] * c2) / s_o;
    double v = fmin(fmax(rint(arg + dit), -128.0), 127.0);
    o8[i] = (int8_t)(int)v;
  }
}

// ---------------- proj bias + max per branch (shared pmax atomic) ----------------
__global__ __launch_bounds__(256) void k_bias_max(
    int* __restrict__ p2, const double* __restrict__ wsp,
    const float* __restrict__ bias, char* __restrict__ ctl, double dit) {
  double s_o = get_so(ctl);
  int n = blockIdx.x;
  int* rowp = p2 + (size_t)n * kC;
  double m = 0.0;
  for (int o = threadIdx.x; o < kC; o += 256) {
    double outs = wsp[o] * s_o;
    double bint = rint((double)bias[o] / outs + dit);
    int a = rowp[o] + (int)bint;
    rowp[o] = a;
    m = fmax(m, fabs((double)a * outs));
  }
  m = wave_max_d(m);
  __shared__ double sred[4];
  if ((threadIdx.x & 63) == 0) sred[threadIdx.x >> 6] = m;
  __syncthreads();
  if (threadIdx.x == 0) {
    double mm = fmax(fmax(sred[0], sred[1]), fmax(sred[2], sred[3]));
    atomicMax((unsigned long long*)(ctl + 16),
              (unsigned long long)__double_as_longlong(mm));
  }
}

// ---------------- final: branch midpoint ----------------
__global__ __launch_bounds__(256) void k_final(
    const int* __restrict__ p2A, const int* __restrict__ p2B,
    const double* __restrict__ wsp,
    const char* __restrict__ ctl, float* __restrict__ out) {
  double s_o = get_so(ctl);
  double s_out = ctl_pmax(ctl) / 32767.0;
  int total = kM * kC;
  for (int i = blockIdx.x * 256 + threadIdx.x; i < total; i += gridDim.x * 256) {
    int o = i % kC;
    double outs = wsp[o] * s_o;
    double vA = fmin(fmax(rint(((double)p2A[i] * outs) / s_out - kEps), -32768.0), 32767.0);
    double vB = fmin(fmax(rint(((double)p2B[i] * outs) / s_out + kEps), -32768.0), 32767.0);
    out[i] = (float)(0.5 * (vA + vB) * s_out);
  }
  if (blockIdx.x == 0 && threadIdx.x == 0) out[total] = (float)s_out;
}

}  // namespace

extern "C" void kernel_launch(void* const* d_in, const int* in_sizes, int n_in,
                              void* d_out, int out_size, void* d_ws, size_t ws_size,
                              hipStream_t stream) {
  const float* x   = (const float*)d_in[0];
  const float* sin = (const float*)d_in[1];
  const float* Wq  = (const float*)d_in[2];
  const float* Wp  = (const float*)d_in[3];
  const float* bp  = (const float*)d_in[4];
  float* out = (float*)d_out;

  char* ws = (char*)d_ws;
  char* ctl = ws;
  size_t off = 1024;
  int8_t* x8   = (int8_t*)(ws + off); off += (size_t)kM * kC;
  int8_t* wq8A = (int8_t*)(ws + off); off += (size_t)kOC * kC;
  int8_t* wq8B = (int8_t*)(ws + off); off += (size_t)kOC * kC;
  int8_t* wp8A = (int8_t*)(ws + off); off += (size_t)kC * kC;
  int8_t* wp8B = (int8_t*)(ws + off); off += (size_t)kC * kC;
  off = (off + 255) & ~(size_t)255;
  double* outs_q = (double*)(ws + off); off += (size_t)kOC * 8;
  double* wsp    = (double*)(ws + off); off += (size_t)kC * 8;
  off = (off + 255) & ~(size_t)255;
  int8_t* qkvA = (int8_t*)(ws + off); off += 3 * SZ_QKV1;
  int8_t* qkvB = (int8_t*)(ws + off); off += 3 * SZ_QKV1;
  int8_t* qA = qkvA, *kA = qkvA + SZ_QKV1, *vA = qkvA + 2 * SZ_QKV1;
  int8_t* qB = qkvB, *kB = qkvB + SZ_QKV1, *vB = qkvB + 2 * SZ_QKV1;
  int8_t* o8A = (int8_t*)(ws + off); off += (size_t)kM * kC;
  int8_t* o8B = (int8_t*)(ws + off); off += (size_t)kM * kC;
  off = (off + 255) & ~(size_t)255;
  // pv dead after quant_o; p2 overlays pv (stream-ordered).
  float* pvA = (float*)(ws + off); int* p2A = (int*)pvA; off += (size_t)kM * kC * 4;
  float* pvB = (float*)(ws + off); int* p2B = (int*)pvB; off += (size_t)kM * kC * 4;

  dim3 g1(kOC / 64, kM / 64);
  hipMemsetAsync(ctl, 0, 1024, stream);
  k_quant_w<<<kOC + kC, 256, 0, stream>>>(Wq, Wp, sin, wq8A, wq8B, wp8A, wp8B,
                                          outs_q, wsp);
  k_quant_x<<<2048, 256, 0, stream>>>(x, sin, x8);
  k_gemm1q<0><<<g1, 256, 0, stream>>>(x8, wq8A, outs_q, ctl, nullptr, 0.0);
  k_gemm1q<0><<<g1, 256, 0, stream>>>(x8, wq8B, outs_q, ctl, nullptr, 0.0);
  k_gemm1q<1><<<g1, 256, 0, stream>>>(x8, wq8A, outs_q, ctl, qkvA, -kEps);
  k_gemm1q<1><<<g1, 256, 0, stream>>>(x8, wq8B, outs_q, ctl, qkvB, +kEps);
  k_qkmax<<<dim3(13, 13, kBH), 256, 0, stream>>>(qA, kA, ctl);
  k_qkmax<<<dim3(13, 13, kBH), 256, 0, stream>>>(qB, kB, ctl);
  k_attn<<<dim3(98, kBH), 256, 0, stream>>>(qA, kA, vA, ctl, pvA, -kEps, -kEpsX0);
  k_attn<<<dim3(98, kBH), 256, 0, stream>>>(qB, kB, vB, ctl, pvB, +kEps, +kEpsX0);
  k_quant_o<<<2048, 256, 0, stream>>>(pvA, ctl, o8A, -kEps);
  k_quant_o<<<2048, 256, 0, stream>>>(pvB, ctl, o8B, +kEps);
  k_gemm_i8<<<dim3(kC / 64, kM / 64), 256, 0, stream>>>(o8A, wp8A, p2A, kC, kC);
  k_gemm_i8<<<dim3(kC / 64, kM / 64), 256, 0, stream>>>(o8B, wp8B, p2B, kC, kC);
  k_bias_max<<<kM, 256, 0, stream>>>(p2A, wsp, bp, ctl, -kEps);
  k_bias_max<<<kM, 256, 0, stream>>>(p2B, wsp, bp, ctl, +kEps);
  k_final<<<2048, 256, 0, stream>>>(p2A, p2B, wsp, ctl, out);
}

// Round 15
// 1809.402 us; speedup vs baseline: 1.4828x; 1.2042x over previous
//
#include <hip/hip_runtime.h>
#include <cstdint>
#include <cstddef>

#define DEV __device__ __forceinline__

namespace {

constexpr int kN = 784, kC = 768, kH = 12, kD = 64;
constexpr int kM = 6272, kOC = 2304, kBH = 96;
constexpr size_t SZ_QKV1 = (size_t)kBH * kN * kD;
constexpr double kEps   = 2.0e-3;        // activation-round dither
constexpr double kEpsW  = 3.0e-5;        // weight-round dither
constexpr double kEpsX0 = 3.0e-5;        // x0 floor dither
constexpr long long kDS = 1024;          // np-f32 exp_sum ambiguity band
constexpr long long kEP = 128;           // np-f32 (p*factor) product ulp band

using i32x4 = __attribute__((ext_vector_type(4))) int;

DEV void mfma_i8_acc(i32x4& c, i32x4 a, i32x4 b) {
  // D = A(16x64 i8) * B(64x16 i8) + C ; exact integer.
  // Builtin (not inline asm): compiler handles MAI hazard wait-states.
  c = __builtin_amdgcn_mfma_i32_16x16x64_i8(a, b, c, 0, 0, 0);
}

DEV int dot4i8(int a, int b, int c) {
#if __has_builtin(__builtin_amdgcn_sdot4)
  return __builtin_amdgcn_sdot4(a, b, c, false);
#else
  return c + (int)(signed char)(a & 0xff)        * (int)(signed char)(b & 0xff)
           + (int)(signed char)((a >> 8) & 0xff) * (int)(signed char)((b >> 8) & 0xff)
           + (int)(signed char)((a >> 16) & 0xff)* (int)(signed char)((b >> 16) & 0xff)
           + (a >> 24) * (b >> 24);
#endif
}

DEV double wave_max_d(double v) {
  for (int o = 32; o; o >>= 1) v = fmax(v, __shfl_xor(v, o));
  return v;
}
DEV int wave_max_i(int v) {
  for (int o = 32; o; o >>= 1) v = max(v, __shfl_xor(v, o));
  return v;
}

// ctl: [0] u64 dbl max|h| ; [8] int max|qk| ; [16] u64 dbl max|proj| ;
// [24] u64 dbl max|pv|
DEV double ctl_hmax(const char* c)  { return __longlong_as_double(*(const long long*)(c)); }
DEV int    ctl_qkmax(const char* c) { return *(const int*)(c + 8); }
DEV double ctl_pmax(const char* c)  { return __longlong_as_double(*(const long long*)(c + 16)); }
DEV double ctl_pvmax(const char* c) { return __longlong_as_double(*(const long long*)(c + 24)); }

DEV double get_s1(const char* c) { return ctl_hmax(c) / 127.0; }
DEV double get_sa(const char* c) {
  double s1 = get_s1(c);
  double amax = ((double)ctl_qkmax(c) * (s1 * s1)) * 0.125;
  return amax / 127.0;
}
DEV double get_c2(const char* c) { return get_s1(c) * 3.0517578125e-05; }
DEV double get_so(const char* c) { return (ctl_pvmax(c) * get_c2(c)) / 127.0; }

// shift-exp of int_softmax, exact integer form. xi <= 0, x0i < 0.
DEV int p_eval(int xi, int x0i) {
  int x2 = xi + (xi >> 1) - (xi >> 4);
  x2 = max(x2, 15 * x0i);
  int q = x2 / x0i;
  int rrem = x2 - x0i * q;
  int base = rrem - 2 * x0i;
  return (q <= 14) ? (base << (14 - q)) : (base >> 1);
}

// Integer 4*P version of r12's p_final — bit-identical values.
DEV int p4_final(long long p, long long fLo, long long fHi) {
  long long a = (p * fLo - kEP) >> 16;
  long long b = (p * fLo + kEP) >> 16;
  if (fLo == fHi) return (int)((a + b) << 1);
  long long c = (p * fHi - kEP) >> 16;
  long long d = (p * fHi + kEP) >> 16;
  return (int)(a + b + c + d);
}

// ---------------- weight quantization: shared scale, dithered A/B ints ----------------
__global__ __launch_bounds__(256) void k_quant_w(
    const float* __restrict__ Wq, const float* __restrict__ Wp,
    const float* __restrict__ s_in_p,
    int8_t* __restrict__ wq8A, int8_t* __restrict__ wq8B,
    int8_t* __restrict__ wp8A, int8_t* __restrict__ wp8B,
    double* __restrict__ outs_q, double* __restrict__ wsp) {
  int r = blockIdx.x;
  bool isq = r < kOC;
  const float* row = isq ? Wq + (size_t)r * kC : Wp + (size_t)(r - kOC) * kC;
  double m = 0.0;
  for (int i = threadIdx.x; i < kC; i += 256) m = fmax(m, fabs((double)row[i]));
  m = wave_max_d(m);
  __shared__ double sred[4];
  __shared__ double s_ws;
  if ((threadIdx.x & 63) == 0) sred[threadIdx.x >> 6] = m;
  __syncthreads();
  if (threadIdx.x == 0) {
    double mm = fmax(fmax(sred[0], sred[1]), fmax(sred[2], sred[3]));
    double ws = mm / 127.0;
    s_ws = ws;
    if (isq) outs_q[r] = ws * (double)s_in_p[0];
    else     wsp[r - kOC] = ws;
  }
  __syncthreads();
  double ws = s_ws;
  int8_t* dA = isq ? wq8A + (size_t)r * kC : wp8A + (size_t)(r - kOC) * kC;
  int8_t* dB = isq ? wq8B + (size_t)r * kC : wp8B + (size_t)(r - kOC) * kC;
  for (int i = threadIdx.x; i < kC; i += 256) {
    double arg = (double)row[i] / ws;
    dA[i] = (int8_t)(int)fmin(fmax(rint(arg - kEpsW), -128.0), 127.0);
    dB[i] = (int8_t)(int)fmin(fmax(rint(arg + kEpsW), -128.0), 127.0);
  }
}

// ---------------- x quantization (exact, shared) ----------------
__global__ __launch_bounds__(256) void k_quant_x(
    const float* __restrict__ x, const float* __restrict__ s_in_p,
    int8_t* __restrict__ x8) {
  double s = (double)s_in_p[0];
  int total = kM * kC;
  for (int i = blockIdx.x * 256 + threadIdx.x; i < total; i += gridDim.x * 256)
    x8[i] = (int8_t)(int)rint((double)x[i] / s);
}

// ---------------- MFMA GEMM1 per branch: MODE 0 hmax, MODE 1 quantize ----------------
// C[m][o] = sum_k A[m][k]*W[o][k], exact int32 via v_mfma_i32_16x16x64_i8.
template <int MODE>
__global__ __launch_bounds__(256) void k_gemm1m(
    const int8_t* __restrict__ A, const int8_t* __restrict__ Bm,
    const double* __restrict__ outs_q, char* __restrict__ ctl,
    int8_t* __restrict__ qkv8, double dit) {
  __shared__ __align__(16) int8_t As[64][80];
  __shared__ __align__(16) int8_t Bs[64][80];
  int bm = blockIdx.y * 64, bn = blockIdx.x * 64;
  int tid = threadIdx.x;
  int lrow = tid >> 2, lcol = (tid & 3) << 4;
  int w = tid >> 6, l = tid & 63;
  int frow = l & 15, fk = (l >> 4) << 4;
  i32x4 acc[4];
#pragma unroll
  for (int s = 0; s < 4; ++s) { acc[s][0] = 0; acc[s][1] = 0; acc[s][2] = 0; acc[s][3] = 0; }
  for (int k0 = 0; k0 < kC; k0 += 64) {
    __syncthreads();
    *(int4*)&As[lrow][lcol] = *(const int4*)&A[(size_t)(bm + lrow) * kC + k0 + lcol];
    *(int4*)&Bs[lrow][lcol] = *(const int4*)&Bm[(size_t)(bn + lrow) * kC + k0 + lcol];
    __syncthreads();
    i32x4 af = *(const i32x4*)&As[w * 16 + frow][fk];
#pragma unroll
    for (int s = 0; s < 4; ++s) {
      i32x4 bf = *(const i32x4*)&Bs[s * 16 + frow][fk];
      mfma_i8_acc(acc[s], af, bf);
    }
  }
  if (MODE == 0) {
    double m = 0.0;
#pragma unroll
    for (int s = 0; s < 4; ++s) {
      double oq = outs_q[bn + s * 16 + frow];
#pragma unroll
      for (int r = 0; r < 4; ++r)
        m = fmax(m, fabs((double)acc[s][r] * oq));
    }
    m = wave_max_d(m);
    __shared__ double sred[4];
    if (l == 0) sred[w] = m;
    __syncthreads();
    if (tid == 0) {
      double mm = fmax(fmax(sred[0], sred[1]), fmax(sred[2], sred[3]));
      atomicMax((unsigned long long*)ctl,
                (unsigned long long)__double_as_longlong(mm));
    }
  } else {
    double s1 = get_s1(ctl);
#pragma unroll
    for (int s = 0; s < 4; ++s) {
      int o = bn + s * 16 + frow;
      double oq = outs_q[o];
      int which = o / kC, rem = o % kC;
      int hh = rem >> 6, dd = rem & 63;
#pragma unroll
      for (int r = 0; r < 4; ++r) {
        int n = bm + w * 16 + ((l >> 4) << 2) + r;
        double arg = ((double)acc[s][r] * oq) / s1;
        double v = fmin(fmax(rint(arg + dit), -128.0), 127.0);
        int bb = n / kN, nn = n % kN;
        qkv8[(size_t)which * SZ_QKV1 + (((size_t)bb * kH + hh) * kN + nn) * kD + dd] =
            (int8_t)(int)v;
      }
    }
  }
}

// ---------------- MFMA proj GEMM (exact int32) ----------------
__global__ __launch_bounds__(256) void k_gemm_i8m(
    const int8_t* __restrict__ A, const int8_t* __restrict__ Bm,
    int* __restrict__ Cout, int Ncols, int K) {
  __shared__ __align__(16) int8_t As[64][80];
  __shared__ __align__(16) int8_t Bs[64][80];
  int bm = blockIdx.y * 64, bn = blockIdx.x * 64;
  int tid = threadIdx.x;
  int lrow = tid >> 2, lcol = (tid & 3) << 4;
  int w = tid >> 6, l = tid & 63;
  int frow = l & 15, fk = (l >> 4) << 4;
  i32x4 acc[4];
#pragma unroll
  for (int s = 0; s < 4; ++s) { acc[s][0] = 0; acc[s][1] = 0; acc[s][2] = 0; acc[s][3] = 0; }
  for (int k0 = 0; k0 < K; k0 += 64) {
    __syncthreads();
    *(int4*)&As[lrow][lcol] = *(const int4*)&A[(size_t)(bm + lrow) * K + k0 + lcol];
    *(int4*)&Bs[lrow][lcol] = *(const int4*)&Bm[(size_t)(bn + lrow) * K + k0 + lcol];
    __syncthreads();
    i32x4 af = *(const i32x4*)&As[w * 16 + frow][fk];
#pragma unroll
    for (int s = 0; s < 4; ++s) {
      i32x4 bf = *(const i32x4*)&Bs[s * 16 + frow][fk];
      mfma_i8_acc(acc[s], af, bf);
    }
  }
#pragma unroll
  for (int s = 0; s < 4; ++s) {
    int n = bn + s * 16 + frow;
#pragma unroll
    for (int r = 0; r < 4; ++r) {
      int m = bm + w * 16 + ((l >> 4) << 2) + r;
      Cout[(size_t)m * Ncols + n] = acc[s][r];
    }
  }
}

// ---------------- MFMA global max |q.k| (int exact; per branch) ----------------
__global__ __launch_bounds__(256) void k_qkmaxm(
    const int8_t* __restrict__ q8, const int8_t* __restrict__ k8,
    char* __restrict__ ctl) {
  __shared__ __align__(16) int8_t As[64][80];
  __shared__ __align__(16) int8_t Bs[64][80];
  int bh = blockIdx.z;
  int n0 = blockIdx.y * 64, m0 = blockIdx.x * 64;
  const int8_t* qb = q8 + (size_t)bh * kN * kD;
  const int8_t* kb = k8 + (size_t)bh * kN * kD;
  int tid = threadIdx.x;
  int lrow = tid >> 2, lcol = (tid & 3) << 4;
  int w = tid >> 6, l = tid & 63;
  int frow = l & 15, fk = (l >> 4) << 4;
  int4 z4 = make_int4(0, 0, 0, 0);
  *(int4*)&As[lrow][lcol] =
      (n0 + lrow < kN) ? *(const int4*)&qb[(size_t)(n0 + lrow) * kD + lcol] : z4;
  *(int4*)&Bs[lrow][lcol] =
      (m0 + lrow < kN) ? *(const int4*)&kb[(size_t)(m0 + lrow) * kD + lcol] : z4;
  __syncthreads();
  i32x4 acc[4];
#pragma unroll
  for (int s = 0; s < 4; ++s) { acc[s][0] = 0; acc[s][1] = 0; acc[s][2] = 0; acc[s][3] = 0; }
  i32x4 af = *(const i32x4*)&As[w * 16 + frow][fk];
#pragma unroll
  for (int s = 0; s < 4; ++s) {
    i32x4 bf = *(const i32x4*)&Bs[s * 16 + frow][fk];
    mfma_i8_acc(acc[s], af, bf);
  }
  int mx = 0;
#pragma unroll
  for (int s = 0; s < 4; ++s)
#pragma unroll
    for (int r = 0; r < 4; ++r) mx = max(mx, abs(acc[s][r]));
  mx = wave_max_i(mx);
  __shared__ int sred[4];
  if (l == 0) sred[w] = mx;
  __syncthreads();
  if (tid == 0) {
    int mm = max(max(sred[0], sred[1]), max(sred[2], sred[3]));
    atomicMax((int*)(ctl + 8), mm);
  }
}

// --- fused attn per branch (QBLK=8, Q in regs, int PV): unchanged from r13 ---
__global__ __launch_bounds__(256) void k_attn(
    const int8_t* __restrict__ q8, const int8_t* __restrict__ k8,
    const int8_t* __restrict__ v8, char* __restrict__ ctl,
    float* __restrict__ pv, double dit, double x0dit) {
  double s1 = get_s1(ctl);
  double s1s1 = s1 * s1;
  double s_a = get_sa(ctl);
  double x0 = floor(-1.0 / s_a + x0dit);

  int bh = blockIdx.y;
  int n0 = blockIdx.x * 8;
  int bb = bh / kH, hh = bh % kH;
  const int8_t* kb = k8 + (size_t)bh * kN * kD;
  const int8_t* vb = v8 + (size_t)bh * kN * kD;

  __shared__ __align__(16) int8_t KVs[64][80];
  __shared__ int8_t AQ[8][832];
  __shared__ __align__(16) int    P4[8][832];

  int tid = threadIdx.x;
  int lr = tid >> 2, lc = (tid & 3) << 4;
  int4 z4 = make_int4(0, 0, 0, 0);

  int qreg[16];
  {
    const int* qrow = (const int*)(q8 + ((size_t)bh * kN + n0 + (tid & 7)) * kD);
#pragma unroll
    for (int t = 0; t < 16; ++t) qreg[t] = qrow[t];
  }

  // phase 1: scores -> quantized attn ints
  {
    int r1 = tid & 7, mb1 = tid >> 3;
    for (int mt = 0; mt < 13; ++mt) {
      int m0 = mt * 64;
      __syncthreads();
      *(int4*)&KVs[lr][lc] =
          (m0 + lr < kN) ? *(const int4*)&kb[(size_t)(m0 + lr) * kD + lc] : z4;
      __syncthreads();
#pragma unroll
      for (int j = 0; j < 2; ++j) {
        int m = mb1 + (j << 5);
        int acc = 0;
#pragma unroll
        for (int kk = 0; kk < 16; ++kk)
          acc = dot4i8(qreg[kk], *(const int*)&KVs[m][kk << 2], acc);
        double attnv = ((double)acc * s1s1) * 0.125;
        double aq = fmin(fmax(rint(attnv / s_a + dit), -128.0), 127.0);
        AQ[r1][m0 + m] = (int8_t)(int)aq;
      }
    }
  }
  __syncthreads();

  // phase 2: integer int_softmax with factor/product ambiguity midpoint (x4 int)
  {
    int x0i = (int)x0;
    int wid = tid >> 6, lane = tid & 63;
    for (int rr = 0; rr < 2; ++rr) {
      int row = wid * 2 + rr;
      int rmax = -128;
      for (int m = lane; m < kN; m += 64) rmax = max(rmax, (int)AQ[row][m]);
      rmax = wave_max_i(rmax);
      long long sd = 0;
      for (int m = lane; m < kN; m += 64) {
        int p = p_eval((int)AQ[row][m] - rmax, x0i);
        P4[row][m] = p;
        sd += p;
      }
      for (int off = 32; off; off >>= 1) sd += __shfl_xor(sd, off);
      long long S = sd > 2147483647LL ? 2147483647LL : sd;
      long long SLo = S + kDS;
      long long SHi = S - kDS; if (SHi < 1) SHi = 1;
      if (SLo > 2147483647LL) SLo = 2147483647LL;
      long long fLo = 2147483647LL / SLo;
      long long fHi = 2147483647LL / SHi;
      for (int m = lane; m < kN; m += 64)
        P4[row][m] = p4_final((long long)P4[row][m], fLo, fHi);
      for (int m = kN + lane; m < 832; m += 64) P4[row][m] = 0;
    }
  }

  // phase 3: integer PV (exact; 0.25*acc64 == r12's f64 accumulation)
  int r3 = tid >> 5, d0 = (tid & 31) << 1;
  long long a64x = 0, a64y = 0;
  for (int mt = 0; mt < 13; ++mt) {
    int m0 = mt * 64;
    __syncthreads();
    *(int4*)&KVs[lr][lc] =
        (m0 + lr < kN) ? *(const int4*)&vb[(size_t)(m0 + lr) * kD + lc] : z4;
    __syncthreads();
    int ax = 0, ay = 0;
#pragma unroll
    for (int m4 = 0; m4 < 16; ++m4) {
      int4 p4v = *(const int4*)&P4[r3][m0 + (m4 << 2)];
      int pp[4] = {p4v.x, p4v.y, p4v.z, p4v.w};
#pragma unroll
      for (int e = 0; e < 4; ++e) {
        int mm = (m4 << 2) + e;
        short sv = *(const short*)&KVs[mm][d0];
        int vx = (int)(int8_t)(sv & 0xff);
        int vy = ((int)sv) >> 8;
        ax += __mul24(pp[e], vx);
        ay += __mul24(pp[e], vy);
      }
    }
    a64x += ax; a64y += ay;
  }
  double v0 = 0.25 * (double)a64x;
  double v1 = 0.25 * (double)a64y;
  size_t obase = ((size_t)bb * kN + (n0 + r3)) * kC + hh * kD + d0;
  pv[obase] = (float)v0;
  pv[obase + 1] = (float)v1;
  double mymax = fmax(fabs(v0), fabs(v1));
  mymax = wave_max_d(mymax);
  __shared__ double sredd[4];
  if ((tid & 63) == 0) sredd[tid >> 6] = mymax;
  __syncthreads();
  if (tid == 0) {
    double mm = fmax(fmax(sredd[0], sredd[1]), fmax(sredd[2], sredd[3]));
    atomicMax((unsigned long long*)(ctl + 24),
              (unsigned long long)__double_as_longlong(mm));
  }
}

// ---------------- quantize attn output per branch (dithered) ----------------
__global__ __launch_bounds__(256) void k_quant_o(
    const float* __restrict__ pv, const char* __restrict__ ctl,
    int8_t* __restrict__ o8, double dit) {
  double c2 = get_c2(ctl);
  double s_o = get_so(ctl);
  int total = kM * kC;
  for (int i = blockIdx.x * 256 + threadIdx.x; i < total; i += gridDim.x * 256) {
    double arg = ((double)pv[i] * c2) / s_o;
    double v = fmin(fmax(rint(arg + dit), -128.0), 127.0);
    o8[i] = (int8_t)(int)v;
  }
}

// ---------------- proj bias + max per branch (shared pmax atomic) ----------------
__global__ __launch_bounds__(256) void k_bias_max(
    int* __restrict__ p2, const double* __restrict__ wsp,
    const float* __restrict__ bias, char* __restrict__ ctl, double dit) {
  double s_o = get_so(ctl);
  int n = blockIdx.x;
  int* rowp = p2 + (size_t)n * kC;
  double m = 0.0;
  for (int o = threadIdx.x; o < kC; o += 256) {
    double outs = wsp[o] * s_o;
    double bint = rint((double)bias[o] / outs + dit);
    int a = rowp[o] + (int)bint;
    rowp[o] = a;
    m = fmax(m, fabs((double)a * outs));
  }
  m = wave_max_d(m);
  __shared__ double sred[4];
  if ((threadIdx.x & 63) == 0) sred[threadIdx.x >> 6] = m;
  __syncthreads();
  if (threadIdx.x == 0) {
    double mm = fmax(fmax(sred[0], sred[1]), fmax(sred[2], sred[3]));
    atomicMax((unsigned long long*)(ctl + 16),
              (unsigned long long)__double_as_longlong(mm));
  }
}

// ---------------- final: branch midpoint ----------------
__global__ __launch_bounds__(256) void k_final(
    const int* __restrict__ p2A, const int* __restrict__ p2B,
    const double* __restrict__ wsp,
    const char* __restrict__ ctl, float* __restrict__ out) {
  double s_o = get_so(ctl);
  double s_out = ctl_pmax(ctl) / 32767.0;
  int total = kM * kC;
  for (int i = blockIdx.x * 256 + threadIdx.x; i < total; i += gridDim.x * 256) {
    int o = i % kC;
    double outs = wsp[o] * s_o;
    double vA = fmin(fmax(rint(((double)p2A[i] * outs) / s_out - kEps), -32768.0), 32767.0);
    double vB = fmin(fmax(rint(((double)p2B[i] * outs) / s_out + kEps), -32768.0), 32767.0);
    out[i] = (float)(0.5 * (vA + vB) * s_out);
  }
  if (blockIdx.x == 0 && threadIdx.x == 0) out[total] = (float)s_out;
}

}  // namespace

extern "C" void kernel_launch(void* const* d_in, const int* in_sizes, int n_in,
                              void* d_out, int out_size, void* d_ws, size_t ws_size,
                              hipStream_t stream) {
  const float* x   = (const float*)d_in[0];
  const float* sin = (const float*)d_in[1];
  const float* Wq  = (const float*)d_in[2];
  const float* Wp  = (const float*)d_in[3];
  const float* bp  = (const float*)d_in[4];
  float* out = (float*)d_out;

  char* ws = (char*)d_ws;
  char* ctl = ws;
  size_t off = 1024;
  int8_t* x8   = (int8_t*)(ws + off); off += (size_t)kM * kC;
  int8_t* wq8A = (int8_t*)(ws + off); off += (size_t)kOC * kC;
  int8_t* wq8B = (int8_t*)(ws + off); off += (size_t)kOC * kC;
  int8_t* wp8A = (int8_t*)(ws + off); off += (size_t)kC * kC;
  int8_t* wp8B = (int8_t*)(ws + off); off += (size_t)kC * kC;
  off = (off + 255) & ~(size_t)255;
  double* outs_q = (double*)(ws + off); off += (size_t)kOC * 8;
  double* wsp    = (double*)(ws + off); off += (size_t)kC * 8;
  off = (off + 255) & ~(size_t)255;
  int8_t* qkvA = (int8_t*)(ws + off); off += 3 * SZ_QKV1;
  int8_t* qkvB = (int8_t*)(ws + off); off += 3 * SZ_QKV1;
  int8_t* qA = qkvA, *kA = qkvA + SZ_QKV1, *vA = qkvA + 2 * SZ_QKV1;
  int8_t* qB = qkvB, *kB = qkvB + SZ_QKV1, *vB = qkvB + 2 * SZ_QKV1;
  int8_t* o8A = (int8_t*)(ws + off); off += (size_t)kM * kC;
  int8_t* o8B = (int8_t*)(ws + off); off += (size_t)kM * kC;
  off = (off + 255) & ~(size_t)255;
  float* pvA = (float*)(ws + off); int* p2A = (int*)pvA; off += (size_t)kM * kC * 4;
  float* pvB = (float*)(ws + off); int* p2B = (int*)pvB; off += (size_t)kM * kC * 4;

  dim3 g1(kOC / 64, kM / 64);
  hipMemsetAsync(ctl, 0, 1024, stream);
  k_quant_w<<<kOC + kC, 256, 0, stream>>>(Wq, Wp, sin, wq8A, wq8B, wp8A, wp8B,
                                          outs_q, wsp);
  k_quant_x<<<2048, 256, 0, stream>>>(x, sin, x8);
  k_gemm1m<0><<<g1, 256, 0, stream>>>(x8, wq8A, outs_q, ctl, nullptr, 0.0);
  k_gemm1m<0><<<g1, 256, 0, stream>>>(x8, wq8B, outs_q, ctl, nullptr, 0.0);
  k_gemm1m<1><<<g1, 256, 0, stream>>>(x8, wq8A, outs_q, ctl, qkvA, -kEps);
  k_gemm1m<1><<<g1, 256, 0, stream>>>(x8, wq8B, outs_q, ctl, qkvB, +kEps);
  k_qkmaxm<<<dim3(13, 13, kBH), 256, 0, stream>>>(qA, kA, ctl);
  k_qkmaxm<<<dim3(13, 13, kBH), 256, 0, stream>>>(qB, kB, ctl);
  k_attn<<<dim3(98, kBH), 256, 0, stream>>>(qA, kA, vA, ctl, pvA, -kEps, -kEpsX0);
  k_attn<<<dim3(98, kBH), 256, 0, stream>>>(qB, kB, vB, ctl, pvB, +kEps, +kEpsX0);
  k_quant_o<<<2048, 256, 0, stream>>>(pvA, ctl, o8A, -kEps);
  k_quant_o<<<2048, 256, 0, stream>>>(pvB, ctl, o8B, +kEps);
  k_gemm_i8m<<<dim3(kC / 64, kM / 64), 256, 0, stream>>>(o8A, wp8A, p2A, kC, kC);
  k_gemm_i8m<<<dim3(kC / 64, kM / 64), 256, 0, stream>>>(o8B, wp8B, p2B, kC, kC);
  k_bias_max<<<kM, 256, 0, stream>>>(p2A, wsp, bp, ctl, -kEps);
  k_bias_max<<<kM, 256, 0, stream>>>(p2B, wsp, bp, ctl, +kEps);
  k_final<<<2048, 256, 0, stream>>>(p2A, p2B, wsp, ctl, out);
}

// Round 16
// 1379.550 us; speedup vs baseline: 1.9449x; 1.3116x over previous
//
#include <hip/hip_runtime.h>
#include <cstdint>
#include <cstddef>

#define DEV __device__ __forceinline__

namespace {

constexpr int kN = 784, kC = 768, kH = 12, kD = 64;
constexpr int kM = 6272, kOC = 2304, kBH = 96;
constexpr int kNp = 832;                 // padded row length for V^T / planes
constexpr size_t SZ_QKV1 = (size_t)kBH * kN * kD;
constexpr size_t SZ_VT   = (size_t)kBH * kD * kNp;
constexpr double kEps   = 2.0e-3;        // activation-round dither
constexpr double kEpsW  = 3.0e-5;        // weight-round dither
constexpr double kEpsX0 = 3.0e-5;        // x0 floor dither
constexpr long long kDS = 1024;          // np-f32 exp_sum ambiguity band
constexpr long long kEP = 128;           // np-f32 (p*factor) product ulp band

using i32x4 = __attribute__((ext_vector_type(4))) int;

DEV void mfma_i8_acc(i32x4& c, i32x4 a, i32x4 b) {
  // D = A(16x64 i8) * B(64x16 i8) + C ; exact integer.
  c = __builtin_amdgcn_mfma_i32_16x16x64_i8(a, b, c, 0, 0, 0);
}

DEV int dot4i8(int a, int b, int c) {
#if __has_builtin(__builtin_amdgcn_sdot4)
  return __builtin_amdgcn_sdot4(a, b, c, false);
#else
  return c + (int)(signed char)(a & 0xff)        * (int)(signed char)(b & 0xff)
           + (int)(signed char)((a >> 8) & 0xff) * (int)(signed char)((b >> 8) & 0xff)
           + (int)(signed char)((a >> 16) & 0xff)* (int)(signed char)((b >> 16) & 0xff)
           + (a >> 24) * (b >> 24);
#endif
}

DEV double wave_max_d(double v) {
  for (int o = 32; o; o >>= 1) v = fmax(v, __shfl_xor(v, o));
  return v;
}
DEV int wave_max_i(int v) {
  for (int o = 32; o; o >>= 1) v = max(v, __shfl_xor(v, o));
  return v;
}

// ctl: [0] u64 dbl max|h| ; [8] int max|qk| ; [16] u64 dbl max|proj| ;
// [24] u64 dbl max|pv|
DEV double ctl_hmax(const char* c)  { return __longlong_as_double(*(const long long*)(c)); }
DEV int    ctl_qkmax(const char* c) { return *(const int*)(c + 8); }
DEV double ctl_pmax(const char* c)  { return __longlong_as_double(*(const long long*)(c + 16)); }
DEV double ctl_pvmax(const char* c) { return __longlong_as_double(*(const long long*)(c + 24)); }

DEV double get_s1(const char* c) { return ctl_hmax(c) / 127.0; }
DEV double get_sa(const char* c) {
  double s1 = get_s1(c);
  double amax = ((double)ctl_qkmax(c) * (s1 * s1)) * 0.125;
  return amax / 127.0;
}
DEV double get_c2(const char* c) { return get_s1(c) * 3.0517578125e-05; }
DEV double get_so(const char* c) { return (ctl_pvmax(c) * get_c2(c)) / 127.0; }

// shift-exp of int_softmax, exact integer form. xi <= 0, x0i < 0.
DEV int p_eval(int xi, int x0i) {
  int x2 = xi + (xi >> 1) - (xi >> 4);
  x2 = max(x2, 15 * x0i);
  int q = x2 / x0i;
  int rrem = x2 - x0i * q;
  int base = rrem - 2 * x0i;
  return (q <= 14) ? (base << (14 - q)) : (base >> 1);
}

// Integer 4*P version of r12's p_final — bit-identical values.
DEV int p4_final(long long p, long long fLo, long long fHi) {
  long long a = (p * fLo - kEP) >> 16;
  long long b = (p * fLo + kEP) >> 16;
  if (fLo == fHi) return (int)((a + b) << 1);
  long long c = (p * fHi - kEP) >> 16;
  long long d = (p * fHi + kEP) >> 16;
  return (int)(a + b + c + d);
}

// ---------------- weight quantization: shared scale, dithered A/B ints ----------------
__global__ __launch_bounds__(256) void k_quant_w(
    const float* __restrict__ Wq, const float* __restrict__ Wp,
    const float* __restrict__ s_in_p,
    int8_t* __restrict__ wq8A, int8_t* __restrict__ wq8B,
    int8_t* __restrict__ wp8A, int8_t* __restrict__ wp8B,
    double* __restrict__ outs_q, double* __restrict__ wsp) {
  int r = blockIdx.x;
  bool isq = r < kOC;
  const float* row = isq ? Wq + (size_t)r * kC : Wp + (size_t)(r - kOC) * kC;
  double m = 0.0;
  for (int i = threadIdx.x; i < kC; i += 256) m = fmax(m, fabs((double)row[i]));
  m = wave_max_d(m);
  __shared__ double sred[4];
  __shared__ double s_ws;
  if ((threadIdx.x & 63) == 0) sred[threadIdx.x >> 6] = m;
  __syncthreads();
  if (threadIdx.x == 0) {
    double mm = fmax(fmax(sred[0], sred[1]), fmax(sred[2], sred[3]));
    double ws = mm / 127.0;
    s_ws = ws;
    if (isq) outs_q[r] = ws * (double)s_in_p[0];
    else     wsp[r - kOC] = ws;
  }
  __syncthreads();
  double ws = s_ws;
  int8_t* dA = isq ? wq8A + (size_t)r * kC : wp8A + (size_t)(r - kOC) * kC;
  int8_t* dB = isq ? wq8B + (size_t)r * kC : wp8B + (size_t)(r - kOC) * kC;
  for (int i = threadIdx.x; i < kC; i += 256) {
    double arg = (double)row[i] / ws;
    dA[i] = (int8_t)(int)fmin(fmax(rint(arg - kEpsW), -128.0), 127.0);
    dB[i] = (int8_t)(int)fmin(fmax(rint(arg + kEpsW), -128.0), 127.0);
  }
}

// ---------------- x quantization (exact, shared) ----------------
__global__ __launch_bounds__(256) void k_quant_x(
    const float* __restrict__ x, const float* __restrict__ s_in_p,
    int8_t* __restrict__ x8) {
  double s = (double)s_in_p[0];
  int total = kM * kC;
  for (int i = blockIdx.x * 256 + threadIdx.x; i < total; i += gridDim.x * 256)
    x8[i] = (int8_t)(int)rint((double)x[i] / s);
}

// ---------------- MFMA GEMM1 per branch: MODE 0 hmax, MODE 1 quantize ----------------
template <int MODE>
__global__ __launch_bounds__(256) void k_gemm1m(
    const int8_t* __restrict__ A, const int8_t* __restrict__ Bm,
    const double* __restrict__ outs_q, char* __restrict__ ctl,
    int8_t* __restrict__ qkv8, int8_t* __restrict__ vT8, double dit) {
  __shared__ __align__(16) int8_t As[64][80];
  __shared__ __align__(16) int8_t Bs[64][80];
  int bm = blockIdx.y * 64, bn = blockIdx.x * 64;
  int tid = threadIdx.x;
  int lrow = tid >> 2, lcol = (tid & 3) << 4;
  int w = tid >> 6, l = tid & 63;
  int frow = l & 15, fk = (l >> 4) << 4;
  i32x4 acc[4];
#pragma unroll
  for (int s = 0; s < 4; ++s) { acc[s][0] = 0; acc[s][1] = 0; acc[s][2] = 0; acc[s][3] = 0; }
  for (int k0 = 0; k0 < kC; k0 += 64) {
    __syncthreads();
    *(int4*)&As[lrow][lcol] = *(const int4*)&A[(size_t)(bm + lrow) * kC + k0 + lcol];
    *(int4*)&Bs[lrow][lcol] = *(const int4*)&Bm[(size_t)(bn + lrow) * kC + k0 + lcol];
    __syncthreads();
    i32x4 af = *(const i32x4*)&As[w * 16 + frow][fk];
#pragma unroll
    for (int s = 0; s < 4; ++s) {
      i32x4 bf = *(const i32x4*)&Bs[s * 16 + frow][fk];
      mfma_i8_acc(acc[s], af, bf);
    }
  }
  if (MODE == 0) {
    double m = 0.0;
#pragma unroll
    for (int s = 0; s < 4; ++s) {
      double oq = outs_q[bn + s * 16 + frow];
#pragma unroll
      for (int r = 0; r < 4; ++r)
        m = fmax(m, fabs((double)acc[s][r] * oq));
    }
    m = wave_max_d(m);
    __shared__ double sred[4];
    if (l == 0) sred[w] = m;
    __syncthreads();
    if (tid == 0) {
      double mm = fmax(fmax(sred[0], sred[1]), fmax(sred[2], sred[3]));
      atomicMax((unsigned long long*)ctl,
                (unsigned long long)__double_as_longlong(mm));
    }
  } else {
    double s1 = get_s1(ctl);
#pragma unroll
    for (int s = 0; s < 4; ++s) {
      int o = bn + s * 16 + frow;
      double oq = outs_q[o];
      int which = o / kC, rem = o % kC;
      int hh = rem >> 6, dd = rem & 63;
#pragma unroll
      for (int r = 0; r < 4; ++r) {
        int n = bm + w * 16 + ((l >> 4) << 2) + r;
        double arg = ((double)acc[s][r] * oq) / s1;
        double v = fmin(fmax(rint(arg + dit), -128.0), 127.0);
        int bb = n / kN, nn = n % kN;
        int8_t q8v = (int8_t)(int)v;
        qkv8[(size_t)which * SZ_QKV1 + (((size_t)bb * kH + hh) * kN + nn) * kD + dd] = q8v;
        if (which == 2)   // V: also write transposed copy for PV MFMA B-fragments
          vT8[((size_t)(bb * kH + hh) * kD + dd) * kNp + nn] = q8v;
      }
    }
  }
}

// ---------------- MFMA proj GEMM (exact int32) ----------------
__global__ __launch_bounds__(256) void k_gemm_i8m(
    const int8_t* __restrict__ A, const int8_t* __restrict__ Bm,
    int* __restrict__ Cout, int Ncols, int K) {
  __shared__ __align__(16) int8_t As[64][80];
  __shared__ __align__(16) int8_t Bs[64][80];
  int bm = blockIdx.y * 64, bn = blockIdx.x * 64;
  int tid = threadIdx.x;
  int lrow = tid >> 2, lcol = (tid & 3) << 4;
  int w = tid >> 6, l = tid & 63;
  int frow = l & 15, fk = (l >> 4) << 4;
  i32x4 acc[4];
#pragma unroll
  for (int s = 0; s < 4; ++s) { acc[s][0] = 0; acc[s][1] = 0; acc[s][2] = 0; acc[s][3] = 0; }
  for (int k0 = 0; k0 < K; k0 += 64) {
    __syncthreads();
    *(int4*)&As[lrow][lcol] = *(const int4*)&A[(size_t)(bm + lrow) * K + k0 + lcol];
    *(int4*)&Bs[lrow][lcol] = *(const int4*)&Bm[(size_t)(bn + lrow) * K + k0 + lcol];
    __syncthreads();
    i32x4 af = *(const i32x4*)&As[w * 16 + frow][fk];
#pragma unroll
    for (int s = 0; s < 4; ++s) {
      i32x4 bf = *(const i32x4*)&Bs[s * 16 + frow][fk];
      mfma_i8_acc(acc[s], af, bf);
    }
  }
#pragma unroll
  for (int s = 0; s < 4; ++s) {
    int n = bn + s * 16 + frow;
#pragma unroll
    for (int r = 0; r < 4; ++r) {
      int m = bm + w * 16 + ((l >> 4) << 2) + r;
      Cout[(size_t)m * Ncols + n] = acc[s][r];
    }
  }
}

// ---------------- MFMA global max |q.k| (int exact; per branch) ----------------
__global__ __launch_bounds__(256) void k_qkmaxm(
    const int8_t* __restrict__ q8, const int8_t* __restrict__ k8,
    char* __restrict__ ctl) {
  __shared__ __align__(16) int8_t As[64][80];
  __shared__ __align__(16) int8_t Bs[64][80];
  int bh = blockIdx.z;
  int n0 = blockIdx.y * 64, m0 = blockIdx.x * 64;
  const int8_t* qb = q8 + (size_t)bh * kN * kD;
  const int8_t* kb = k8 + (size_t)bh * kN * kD;
  int tid = threadIdx.x;
  int lrow = tid >> 2, lcol = (tid & 3) << 4;
  int w = tid >> 6, l = tid & 63;
  int frow = l & 15, fk = (l >> 4) << 4;
  int4 z4 = make_int4(0, 0, 0, 0);
  *(int4*)&As[lrow][lcol] =
      (n0 + lrow < kN) ? *(const int4*)&qb[(size_t)(n0 + lrow) * kD + lcol] : z4;
  *(int4*)&Bs[lrow][lcol] =
      (m0 + lrow < kN) ? *(const int4*)&kb[(size_t)(m0 + lrow) * kD + lcol] : z4;
  __syncthreads();
  i32x4 acc[4];
#pragma unroll
  for (int s = 0; s < 4; ++s) { acc[s][0] = 0; acc[s][1] = 0; acc[s][2] = 0; acc[s][3] = 0; }
  i32x4 af = *(const i32x4*)&As[w * 16 + frow][fk];
#pragma unroll
  for (int s = 0; s < 4; ++s) {
    i32x4 bf = *(const i32x4*)&Bs[s * 16 + frow][fk];
    mfma_i8_acc(acc[s], af, bf);
  }
  int mx = 0;
#pragma unroll
  for (int s = 0; s < 4; ++s)
#pragma unroll
    for (int r = 0; r < 4; ++r) mx = max(mx, abs(acc[s][r]));
  mx = wave_max_i(mx);
  __shared__ int sred[4];
  if (l == 0) sred[w] = mx;
  __syncthreads();
  if (tid == 0) {
    int mm = max(max(sred[0], sred[1]), max(sred[2], sred[3]));
    atomicMax((int*)(ctl + 8), mm);
  }
}

// --- fused attn per branch (QBLK=8): dot4 QK^T + int softmax + MFMA PV ---
// PV via exact 3-plane signed-byte decomposition: P4 = b0 + 256*b1 + 65536*b2,
// D = D0 + (D1<<8) + (D2<<16) in int64 == sum P4*v exactly (== r13 semantics).
__global__ __launch_bounds__(256) void k_attn(
    const int8_t* __restrict__ q8, const int8_t* __restrict__ k8,
    const int8_t* __restrict__ vT8, char* __restrict__ ctl,
    float* __restrict__ pv, double dit, double x0dit) {
  double s1 = get_s1(ctl);
  double s1s1 = s1 * s1;
  double s_a = get_sa(ctl);
  double x0 = floor(-1.0 / s_a + x0dit);

  int bh = blockIdx.y;
  int n0 = blockIdx.x * 8;
  int bb = bh / kH, hh = bh % kH;
  const int8_t* kb = k8 + (size_t)bh * kN * kD;

  __shared__ __align__(16) int8_t KVs[64][80];
  __shared__ int8_t AQ[8][832];
  __shared__ __align__(16) int8_t PL[3][8][848];   // digit planes, stride 848

  int tid = threadIdx.x;
  int lr = tid >> 2, lc = (tid & 3) << 4;
  int4 z4 = make_int4(0, 0, 0, 0);

  int qreg[16];
  {
    const int* qrow = (const int*)(q8 + ((size_t)bh * kN + n0 + (tid & 7)) * kD);
#pragma unroll
    for (int t = 0; t < 16; ++t) qreg[t] = qrow[t];
  }

  // phase 1: scores -> quantized attn ints (identical f64 expression to r13)
  {
    int r1 = tid & 7, mb1 = tid >> 3;
    for (int mt = 0; mt < 13; ++mt) {
      int m0 = mt * 64;
      __syncthreads();
      *(int4*)&KVs[lr][lc] =
          (m0 + lr < kN) ? *(const int4*)&kb[(size_t)(m0 + lr) * kD + lc] : z4;
      __syncthreads();
#pragma unroll
      for (int j = 0; j < 2; ++j) {
        int m = mb1 + (j << 5);
        int acc = 0;
#pragma unroll
        for (int kk = 0; kk < 16; ++kk)
          acc = dot4i8(qreg[kk], *(const int*)&KVs[m][kk << 2], acc);
        double attnv = ((double)acc * s1s1) * 0.125;
        double aq = fmin(fmax(rint(attnv / s_a + dit), -128.0), 127.0);
        AQ[r1][m0 + m] = (int8_t)(int)aq;
      }
    }
  }
  __syncthreads();

  // phase 2: integer int_softmax -> digit planes (values == r13's P4, exact)
  {
    int x0i = (int)x0;
    int wid = tid >> 6, lane = tid & 63;
    for (int rr = 0; rr < 2; ++rr) {
      int row = wid * 2 + rr;
      int rmax = -128;
      for (int m = lane; m < kN; m += 64) rmax = max(rmax, (int)AQ[row][m]);
      rmax = wave_max_i(rmax);
      long long sd = 0;
      for (int m = lane; m < kN; m += 64)
        sd += p_eval((int)AQ[row][m] - rmax, x0i);
      for (int off = 32; off; off >>= 1) sd += __shfl_xor(sd, off);
      long long S = sd > 2147483647LL ? 2147483647LL : sd;
      long long SLo = S + kDS;
      long long SHi = S - kDS; if (SHi < 1) SHi = 1;
      if (SLo > 2147483647LL) SLo = 2147483647LL;
      long long fLo = 2147483647LL / SLo;
      long long fHi = 2147483647LL / SHi;
      for (int m = lane; m < kN; m += 64) {
        int p4 = p4_final((long long)p_eval((int)AQ[row][m] - rmax, x0i), fLo, fHi);
        int b0 = (int)(int8_t)(p4 & 0xff);
        int t1 = (p4 - b0) >> 8;          // exact
        int b1 = (int)(int8_t)(t1 & 0xff);
        int b2 = (t1 - b1) >> 8;          // in [0,3]
        PL[0][row][m] = (int8_t)b0;
        PL[1][row][m] = (int8_t)b1;
        PL[2][row][m] = (int8_t)b2;
      }
      for (int m = kN + lane; m < 832; m += 64) {
        PL[0][row][m] = 0; PL[1][row][m] = 0; PL[2][row][m] = 0;
      }
    }
  }
  __syncthreads();

  // phase 3: MFMA PV — per wave one 16-d subtile; accumulate over all m.
  {
    int w = tid >> 6, l = tid & 63;
    int frow = (l & 15) & 7;             // A row (rows 8..15 duplicate 0..7)
    int fk = (l >> 4) << 4;
    int dglob = w * 16 + (l & 15);
    const int8_t* vtb = vT8 + ((size_t)bh * kD + dglob) * kNp;
    i32x4 a0, a1, a2;
    a0[0]=0;a0[1]=0;a0[2]=0;a0[3]=0;
    a1[0]=0;a1[1]=0;a1[2]=0;a1[3]=0;
    a2[0]=0;a2[1]=0;a2[2]=0;a2[3]=0;
    for (int mt = 0; mt < 13; ++mt) {
      int m0 = mt * 64;
      i32x4 bf = *(const i32x4*)&vtb[m0 + fk];
      i32x4 f0 = *(const i32x4*)&PL[0][frow][m0 + fk];
      i32x4 f1 = *(const i32x4*)&PL[1][frow][m0 + fk];
      i32x4 f2 = *(const i32x4*)&PL[2][frow][m0 + fk];
      mfma_i8_acc(a0, f0, bf);
      mfma_i8_acc(a1, f1, bf);
      mfma_i8_acc(a2, f2, bf);
    }
    double mymax = 0.0;
    int qhi = l >> 4;
#pragma unroll
    for (int r = 0; r < 4; ++r) {
      int q = qhi * 4 + r;
      if (q < 8) {
        long long tot = (long long)a0[r] + ((long long)a1[r] << 8) +
                        ((long long)a2[r] << 16);
        double v = 0.25 * (double)tot;
        pv[((size_t)bb * kN + (n0 + q)) * kC + hh * kD + dglob] = (float)v;
        mymax = fmax(mymax, fabs(v));
      }
    }
    mymax = wave_max_d(mymax);
    __shared__ double sredd[4];
    if (l == 0) sredd[w] = mymax;
    __syncthreads();
    if (tid == 0) {
      double mm = fmax(fmax(sredd[0], sredd[1]), fmax(sredd[2], sredd[3]));
      atomicMax((unsigned long long*)(ctl + 24),
                (unsigned long long)__double_as_longlong(mm));
    }
  }
}

// ---------------- quantize attn output per branch (dithered) ----------------
__global__ __launch_bounds__(256) void k_quant_o(
    const float* __restrict__ pv, const char* __restrict__ ctl,
    int8_t* __restrict__ o8, double dit) {
  double c2 = get_c2(ctl);
  double s_o = get_so(ctl);
  int total = kM * kC;
  for (int i = blockIdx.x * 256 + threadIdx.x; i < total; i += gridDim.x * 256) {
    double arg = ((double)pv[i] * c2) / s_o;
    double v = fmin(fmax(rint(arg + dit), -128.0), 127.0);
    o8[i] = (int8_t)(int)v;
  }
}

// ---------------- proj bias + max per branch (shared pmax atomic) ----------------
__global__ __launch_bounds__(256) void k_bias_max(
    int* __restrict__ p2, const double* __restrict__ wsp,
    const float* __restrict__ bias, char* __restrict__ ctl, double dit) {
  double s_o = get_so(ctl);
  int n = blockIdx.x;
  int* rowp = p2 + (size_t)n * kC;
  double m = 0.0;
  for (int o = threadIdx.x; o < kC; o += 256) {
    double outs = wsp[o] * s_o;
    double bint = rint((double)bias[o] / outs + dit);
    int a = rowp[o] + (int)bint;
    rowp[o] = a;
    m = fmax(m, fabs((double)a * outs));
  }
  m = wave_max_d(m);
  __shared__ double sred[4];
  if ((threadIdx.x & 63) == 0) sred[threadIdx.x >> 6] = m;
  __syncthreads();
  if (threadIdx.x == 0) {
    double mm = fmax(fmax(sred[0], sred[1]), fmax(sred[2], sred[3]));
    atomicMax((unsigned long long*)(ctl + 16),
              (unsigned long long)__double_as_longlong(mm));
  }
}

// ---------------- final: branch midpoint ----------------
__global__ __launch_bounds__(256) void k_final(
    const int* __restrict__ p2A, const int* __restrict__ p2B,
    const double* __restrict__ wsp,
    const char* __restrict__ ctl, float* __restrict__ out) {
  double s_o = get_so(ctl);
  double s_out = ctl_pmax(ctl) / 32767.0;
  int total = kM * kC;
  for (int i = blockIdx.x * 256 + threadIdx.x; i < total; i += gridDim.x * 256) {
    int o = i % kC;
    double outs = wsp[o] * s_o;
    double vA = fmin(fmax(rint(((double)p2A[i] * outs) / s_out - kEps), -32768.0), 32767.0);
    double vB = fmin(fmax(rint(((double)p2B[i] * outs) / s_out + kEps), -32768.0), 32767.0);
    out[i] = (float)(0.5 * (vA + vB) * s_out);
  }
  if (blockIdx.x == 0 && threadIdx.x == 0) out[total] = (float)s_out;
}

}  // namespace

extern "C" void kernel_launch(void* const* d_in, const int* in_sizes, int n_in,
                              void* d_out, int out_size, void* d_ws, size_t ws_size,
                              hipStream_t stream) {
  const float* x   = (const float*)d_in[0];
  const float* sin = (const float*)d_in[1];
  const float* Wq  = (const float*)d_in[2];
  const float* Wp  = (const float*)d_in[3];
  const float* bp  = (const float*)d_in[4];
  float* out = (float*)d_out;

  char* ws = (char*)d_ws;
  char* ctl = ws;
  size_t off = 1024;
  int8_t* x8   = (int8_t*)(ws + off); off += (size_t)kM * kC;
  int8_t* wq8A = (int8_t*)(ws + off); off += (size_t)kOC * kC;
  int8_t* wq8B = (int8_t*)(ws + off); off += (size_t)kOC * kC;
  int8_t* wp8A = (int8_t*)(ws + off); off += (size_t)kC * kC;
  int8_t* wp8B = (int8_t*)(ws + off); off += (size_t)kC * kC;
  off = (off + 255) & ~(size_t)255;
  double* outs_q = (double*)(ws + off); off += (size_t)kOC * 8;
  double* wsp    = (double*)(ws + off); off += (size_t)kC * 8;
  off = (off + 255) & ~(size_t)255;
  int8_t* qkvA = (int8_t*)(ws + off); off += 3 * SZ_QKV1;
  int8_t* qkvB = (int8_t*)(ws + off); off += 3 * SZ_QKV1;
  int8_t* qA = qkvA, *kA = qkvA + SZ_QKV1;
  int8_t* qB = qkvB, *kB = qkvB + SZ_QKV1;
  off = (off + 255) & ~(size_t)255;
  int8_t* vT8A = (int8_t*)(ws + off); off += SZ_VT;
  int8_t* vT8B = (int8_t*)(ws + off); off += SZ_VT;
  int8_t* o8A = (int8_t*)(ws + off); off += (size_t)kM * kC;
  int8_t* o8B = (int8_t*)(ws + off); off += (size_t)kM * kC;
  off = (off + 255) & ~(size_t)255;
  float* pvA = (float*)(ws + off); int* p2A = (int*)pvA; off += (size_t)kM * kC * 4;
  float* pvB = (float*)(ws + off); int* p2B = (int*)pvB; off += (size_t)kM * kC * 4;

  dim3 g1(kOC / 64, kM / 64);
  hipMemsetAsync(ctl, 0, 1024, stream);
  k_quant_w<<<kOC + kC, 256, 0, stream>>>(Wq, Wp, sin, wq8A, wq8B, wp8A, wp8B,
                                          outs_q, wsp);
  k_quant_x<<<2048, 256, 0, stream>>>(x, sin, x8);
  k_gemm1m<0><<<g1, 256, 0, stream>>>(x8, wq8A, outs_q, ctl, nullptr, nullptr, 0.0);
  k_gemm1m<0><<<g1, 256, 0, stream>>>(x8, wq8B, outs_q, ctl, nullptr, nullptr, 0.0);
  k_gemm1m<1><<<g1, 256, 0, stream>>>(x8, wq8A, outs_q, ctl, qkvA, vT8A, -kEps);
  k_gemm1m<1><<<g1, 256, 0, stream>>>(x8, wq8B, outs_q, ctl, qkvB, vT8B, +kEps);
  k_qkmaxm<<<dim3(13, 13, kBH), 256, 0, stream>>>(qA, kA, ctl);
  k_qkmaxm<<<dim3(13, 13, kBH), 256, 0, stream>>>(qB, kB, ctl);
  k_attn<<<dim3(98, kBH), 256, 0, stream>>>(qA, kA, vT8A, ctl, pvA, -kEps, -kEpsX0);
  k_attn<<<dim3(98, kBH), 256, 0, stream>>>(qB, kB, vT8B, ctl, pvB, +kEps, +kEpsX0);
  k_quant_o<<<2048, 256, 0, stream>>>(pvA, ctl, o8A, -kEps);
  k_quant_o<<<2048, 256, 0, stream>>>(pvB, ctl, o8B, +kEps);
  k_gemm_i8m<<<dim3(kC / 64, kM / 64), 256, 0, stream>>>(o8A, wp8A, p2A, kC, kC);
  k_gemm_i8m<<<dim3(kC / 64, kM / 64), 256, 0, stream>>>(o8B, wp8B, p2B, kC, kC);
  k_bias_max<<<kM, 256, 0, stream>>>(p2A, wsp, bp, ctl, -kEps);
  k_bias_max<<<kM, 256, 0, stream>>>(p2B, wsp, bp, ctl, +kEps);
  k_final<<<2048, 256, 0, stream>>>(p2A, p2B, wsp, ctl, out);
}

// Round 17
// 1343.452 us; speedup vs baseline: 1.9971x; 1.0269x over previous
//
#include <hip/hip_runtime.h>
#include <cstdint>
#include <cstddef>

#define DEV __device__ __forceinline__

namespace {

constexpr int kN = 784, kC = 768, kH = 12, kD = 64;
constexpr int kM = 6272, kOC = 2304, kBH = 96;
constexpr int kNp = 832;                 // padded row length for V^T / planes
constexpr size_t SZ_QKV1 = (size_t)kBH * kN * kD;
constexpr size_t SZ_VT   = (size_t)kBH * kD * kNp;
constexpr double kEps   = 2.0e-3;        // activation-round dither
constexpr double kEpsW  = 3.0e-5;        // weight-round dither
constexpr double kEpsX0 = 3.0e-5;        // x0 floor dither
constexpr long long kDS = 1024;          // np-f32 exp_sum ambiguity band
constexpr long long kEP = 128;           // np-f32 (p*factor) product ulp band

using i32x4 = __attribute__((ext_vector_type(4))) int;

DEV void mfma_i8_acc(i32x4& c, i32x4 a, i32x4 b) {
  // D = A(16x64 i8) * B(64x16 i8) + C ; exact integer.
  c = __builtin_amdgcn_mfma_i32_16x16x64_i8(a, b, c, 0, 0, 0);
}

DEV int dot4i8(int a, int b, int c) {
#if __has_builtin(__builtin_amdgcn_sdot4)
  return __builtin_amdgcn_sdot4(a, b, c, false);
#else
  return c + (int)(signed char)(a & 0xff)        * (int)(signed char)(b & 0xff)
           + (int)(signed char)((a >> 8) & 0xff) * (int)(signed char)((b >> 8) & 0xff)
           + (int)(signed char)((a >> 16) & 0xff)* (int)(signed char)((b >> 16) & 0xff)
           + (a >> 24) * (b >> 24);
#endif
}

DEV double wave_max_d(double v) {
  for (int o = 32; o; o >>= 1) v = fmax(v, __shfl_xor(v, o));
  return v;
}
DEV int wave_max_i(int v) {
  for (int o = 32; o; o >>= 1) v = max(v, __shfl_xor(v, o));
  return v;
}

// ctl: [0] u64 dbl max|h| ; [8] int max|qk| ; [16] u64 dbl max|proj| ;
// [24] u64 dbl max|pv|
DEV double ctl_hmax(const char* c)  { return __longlong_as_double(*(const long long*)(c)); }
DEV int    ctl_qkmax(const char* c) { return *(const int*)(c + 8); }
DEV double ctl_pmax(const char* c)  { return __longlong_as_double(*(const long long*)(c + 16)); }
DEV double ctl_pvmax(const char* c) { return __longlong_as_double(*(const long long*)(c + 24)); }

DEV double get_s1(const char* c) { return ctl_hmax(c) / 127.0; }
DEV double get_sa(const char* c) {
  double s1 = get_s1(c);
  double amax = ((double)ctl_qkmax(c) * (s1 * s1)) * 0.125;
  return amax / 127.0;
}
DEV double get_c2(const char* c) { return get_s1(c) * 3.0517578125e-05; }
DEV double get_so(const char* c) { return (ctl_pvmax(c) * get_c2(c)) / 127.0; }

// shift-exp of int_softmax, exact integer form. xi <= 0, x0i < 0.
DEV int p_eval(int xi, int x0i) {
  int x2 = xi + (xi >> 1) - (xi >> 4);
  x2 = max(x2, 15 * x0i);
  int q = x2 / x0i;
  int rrem = x2 - x0i * q;
  int base = rrem - 2 * x0i;
  return (q <= 14) ? (base << (14 - q)) : (base >> 1);
}

// Integer 4*P version of r12's p_final — bit-identical values.
DEV int p4_final(long long p, long long fLo, long long fHi) {
  long long a = (p * fLo - kEP) >> 16;
  long long b = (p * fLo + kEP) >> 16;
  if (fLo == fHi) return (int)((a + b) << 1);
  long long c = (p * fHi - kEP) >> 16;
  long long d = (p * fHi + kEP) >> 16;
  return (int)(a + b + c + d);
}

// ---------------- weight quantization: shared scale, dithered A/B ints ----------------
__global__ __launch_bounds__(256) void k_quant_w(
    const float* __restrict__ Wq, const float* __restrict__ Wp,
    const float* __restrict__ s_in_p,
    int8_t* __restrict__ wq8A, int8_t* __restrict__ wq8B,
    int8_t* __restrict__ wp8A, int8_t* __restrict__ wp8B,
    double* __restrict__ outs_q, double* __restrict__ wsp) {
  int r = blockIdx.x;
  bool isq = r < kOC;
  const float* row = isq ? Wq + (size_t)r * kC : Wp + (size_t)(r - kOC) * kC;
  double m = 0.0;
  for (int i = threadIdx.x; i < kC; i += 256) m = fmax(m, fabs((double)row[i]));
  m = wave_max_d(m);
  __shared__ double sred[4];
  __shared__ double s_ws;
  if ((threadIdx.x & 63) == 0) sred[threadIdx.x >> 6] = m;
  __syncthreads();
  if (threadIdx.x == 0) {
    double mm = fmax(fmax(sred[0], sred[1]), fmax(sred[2], sred[3]));
    double ws = mm / 127.0;
    s_ws = ws;
    if (isq) outs_q[r] = ws * (double)s_in_p[0];
    else     wsp[r - kOC] = ws;
  }
  __syncthreads();
  double ws = s_ws;
  int8_t* dA = isq ? wq8A + (size_t)r * kC : wp8A + (size_t)(r - kOC) * kC;
  int8_t* dB = isq ? wq8B + (size_t)r * kC : wp8B + (size_t)(r - kOC) * kC;
  for (int i = threadIdx.x; i < kC; i += 256) {
    double arg = (double)row[i] / ws;
    dA[i] = (int8_t)(int)fmin(fmax(rint(arg - kEpsW), -128.0), 127.0);
    dB[i] = (int8_t)(int)fmin(fmax(rint(arg + kEpsW), -128.0), 127.0);
  }
}

// ---------------- x quantization (exact, shared) ----------------
__global__ __launch_bounds__(256) void k_quant_x(
    const float* __restrict__ x, const float* __restrict__ s_in_p,
    int8_t* __restrict__ x8) {
  double s = (double)s_in_p[0];
  int total = kM * kC;
  for (int i = blockIdx.x * 256 + threadIdx.x; i < total; i += gridDim.x * 256)
    x8[i] = (int8_t)(int)rint((double)x[i] / s);
}

// ------------- 128x128-tile MFMA GEMM1 per branch: MODE 0 hmax, MODE 1 quantize -------------
template <int MODE>
__global__ __launch_bounds__(256) void k_gemm1m(
    const int8_t* __restrict__ A, const int8_t* __restrict__ Bm,
    const double* __restrict__ outs_q, char* __restrict__ ctl,
    int8_t* __restrict__ qkv8, int8_t* __restrict__ vT8, double dit) {
  __shared__ __align__(16) int8_t As[128][80];
  __shared__ __align__(16) int8_t Bs[128][80];
  int bm = blockIdx.y * 128, bn = blockIdx.x * 128;
  int tid = threadIdx.x;
  int w = tid >> 6, l = tid & 63;
  int frow = l & 15, fk = (l >> 4) << 4;
  int rb = w * 32;
  i32x4 acc[2][8];
#pragma unroll
  for (int i = 0; i < 2; ++i)
#pragma unroll
    for (int s = 0; s < 8; ++s) { acc[i][s][0]=0; acc[i][s][1]=0; acc[i][s][2]=0; acc[i][s][3]=0; }
  for (int k0 = 0; k0 < kC; k0 += 64) {
    __syncthreads();
#pragma unroll
    for (int e = 0; e < 2; ++e) {
      int idx = tid + e * 256;
      int row = idx >> 2, cg = (idx & 3) << 4;
      *(int4*)&As[row][cg] = *(const int4*)&A[(size_t)(bm + row) * kC + k0 + cg];
      *(int4*)&Bs[row][cg] = *(const int4*)&Bm[(size_t)(bn + row) * kC + k0 + cg];
    }
    __syncthreads();
    i32x4 af0 = *(const i32x4*)&As[rb + frow][fk];
    i32x4 af1 = *(const i32x4*)&As[rb + 16 + frow][fk];
#pragma unroll
    for (int s = 0; s < 8; ++s) {
      i32x4 bf = *(const i32x4*)&Bs[s * 16 + frow][fk];
      mfma_i8_acc(acc[0][s], af0, bf);
      mfma_i8_acc(acc[1][s], af1, bf);
    }
  }
  if (MODE == 0) {
    double m = 0.0;
#pragma unroll
    for (int s = 0; s < 8; ++s) {
      double oq = outs_q[bn + s * 16 + frow];
#pragma unroll
      for (int i = 0; i < 2; ++i)
#pragma unroll
        for (int r = 0; r < 4; ++r)
          m = fmax(m, fabs((double)acc[i][s][r] * oq));
    }
    m = wave_max_d(m);
    __shared__ double sred[4];
    if (l == 0) sred[w] = m;
    __syncthreads();
    if (tid == 0) {
      double mm = fmax(fmax(sred[0], sred[1]), fmax(sred[2], sred[3]));
      atomicMax((unsigned long long*)ctl,
                (unsigned long long)__double_as_longlong(mm));
    }
  } else {
    double s1 = get_s1(ctl);
#pragma unroll
    for (int s = 0; s < 8; ++s) {
      int o = bn + s * 16 + frow;
      double oq = outs_q[o];
      int which = o / kC, rem = o % kC;
      int hh = rem >> 6, dd = rem & 63;
#pragma unroll
      for (int i = 0; i < 2; ++i)
#pragma unroll
        for (int r = 0; r < 4; ++r) {
          int n = bm + rb + i * 16 + ((l >> 4) << 2) + r;
          double arg = ((double)acc[i][s][r] * oq) / s1;
          double v = fmin(fmax(rint(arg + dit), -128.0), 127.0);
          int bb = n / kN, nn = n % kN;
          int8_t q8v = (int8_t)(int)v;
          qkv8[(size_t)which * SZ_QKV1 + (((size_t)bb * kH + hh) * kN + nn) * kD + dd] = q8v;
          if (which == 2)
            vT8[((size_t)(bb * kH + hh) * kD + dd) * kNp + nn] = q8v;
        }
    }
  }
}

// ---------------- 128x128 MFMA proj GEMM (exact int32) ----------------
__global__ __launch_bounds__(256) void k_gemm_i8m(
    const int8_t* __restrict__ A, const int8_t* __restrict__ Bm,
    int* __restrict__ Cout, int Ncols, int K) {
  __shared__ __align__(16) int8_t As[128][80];
  __shared__ __align__(16) int8_t Bs[128][80];
  int bm = blockIdx.y * 128, bn = blockIdx.x * 128;
  int tid = threadIdx.x;
  int w = tid >> 6, l = tid & 63;
  int frow = l & 15, fk = (l >> 4) << 4;
  int rb = w * 32;
  i32x4 acc[2][8];
#pragma unroll
  for (int i = 0; i < 2; ++i)
#pragma unroll
    for (int s = 0; s < 8; ++s) { acc[i][s][0]=0; acc[i][s][1]=0; acc[i][s][2]=0; acc[i][s][3]=0; }
  for (int k0 = 0; k0 < K; k0 += 64) {
    __syncthreads();
#pragma unroll
    for (int e = 0; e < 2; ++e) {
      int idx = tid + e * 256;
      int row = idx >> 2, cg = (idx & 3) << 4;
      *(int4*)&As[row][cg] = *(const int4*)&A[(size_t)(bm + row) * K + k0 + cg];
      *(int4*)&Bs[row][cg] = *(const int4*)&Bm[(size_t)(bn + row) * K + k0 + cg];
    }
    __syncthreads();
    i32x4 af0 = *(const i32x4*)&As[rb + frow][fk];
    i32x4 af1 = *(const i32x4*)&As[rb + 16 + frow][fk];
#pragma unroll
    for (int s = 0; s < 8; ++s) {
      i32x4 bf = *(const i32x4*)&Bs[s * 16 + frow][fk];
      mfma_i8_acc(acc[0][s], af0, bf);
      mfma_i8_acc(acc[1][s], af1, bf);
    }
  }
#pragma unroll
  for (int s = 0; s < 8; ++s) {
    int n = bn + s * 16 + frow;
#pragma unroll
    for (int i = 0; i < 2; ++i)
#pragma unroll
      for (int r = 0; r < 4; ++r) {
        int m = bm + rb + i * 16 + ((l >> 4) << 2) + r;
        Cout[(size_t)m * Ncols + n] = acc[i][s][r];
      }
  }
}

// ---------------- MFMA global max |q.k| (int exact; per branch) ----------------
__global__ __launch_bounds__(256) void k_qkmaxm(
    const int8_t* __restrict__ q8, const int8_t* __restrict__ k8,
    char* __restrict__ ctl) {
  __shared__ __align__(16) int8_t As[64][80];
  __shared__ __align__(16) int8_t Bs[64][80];
  int bh = blockIdx.z;
  int n0 = blockIdx.y * 64, m0 = blockIdx.x * 64;
  const int8_t* qb = q8 + (size_t)bh * kN * kD;
  const int8_t* kb = k8 + (size_t)bh * kN * kD;
  int tid = threadIdx.x;
  int lrow = tid >> 2, lcol = (tid & 3) << 4;
  int w = tid >> 6, l = tid & 63;
  int frow = l & 15, fk = (l >> 4) << 4;
  int4 z4 = make_int4(0, 0, 0, 0);
  *(int4*)&As[lrow][lcol] =
      (n0 + lrow < kN) ? *(const int4*)&qb[(size_t)(n0 + lrow) * kD + lcol] : z4;
  *(int4*)&Bs[lrow][lcol] =
      (m0 + lrow < kN) ? *(const int4*)&kb[(size_t)(m0 + lrow) * kD + lcol] : z4;
  __syncthreads();
  i32x4 acc[4];
#pragma unroll
  for (int s = 0; s < 4; ++s) { acc[s][0] = 0; acc[s][1] = 0; acc[s][2] = 0; acc[s][3] = 0; }
  i32x4 af = *(const i32x4*)&As[w * 16 + frow][fk];
#pragma unroll
  for (int s = 0; s < 4; ++s) {
    i32x4 bf = *(const i32x4*)&Bs[s * 16 + frow][fk];
    mfma_i8_acc(acc[s], af, bf);
  }
  int mx = 0;
#pragma unroll
  for (int s = 0; s < 4; ++s)
#pragma unroll
    for (int r = 0; r < 4; ++r) mx = max(mx, abs(acc[s][r]));
  mx = wave_max_i(mx);
  __shared__ int sred[4];
  if (l == 0) sred[w] = mx;
  __syncthreads();
  if (tid == 0) {
    int mm = max(max(sred[0], sred[1]), max(sred[2], sred[3]));
    atomicMax((int*)(ctl + 8), mm);
  }
}

// --- fused attn per branch (QBLK=8): dot4 QK^T + int softmax + MFMA PV ---
__global__ __launch_bounds__(256) void k_attn(
    const int8_t* __restrict__ q8, const int8_t* __restrict__ k8,
    const int8_t* __restrict__ vT8, char* __restrict__ ctl,
    float* __restrict__ pv, double dit, double x0dit) {
  double s1 = get_s1(ctl);
  double s1s1 = s1 * s1;
  double s_a = get_sa(ctl);
  double x0 = floor(-1.0 / s_a + x0dit);

  int bh = blockIdx.y;
  int n0 = blockIdx.x * 8;
  int bb = bh / kH, hh = bh % kH;
  const int8_t* kb = k8 + (size_t)bh * kN * kD;

  __shared__ __align__(16) int8_t KVs[64][80];
  __shared__ int8_t AQ[8][832];
  __shared__ __align__(16) int8_t PL[3][8][848];   // digit planes, stride 848

  int tid = threadIdx.x;
  int lr = tid >> 2, lc = (tid & 3) << 4;
  int4 z4 = make_int4(0, 0, 0, 0);

  int qreg[16];
  {
    const int* qrow = (const int*)(q8 + ((size_t)bh * kN + n0 + (tid & 7)) * kD);
#pragma unroll
    for (int t = 0; t < 16; ++t) qreg[t] = qrow[t];
  }

  // phase 1: scores -> quantized attn ints (identical f64 expression to r13)
  {
    int r1 = tid & 7, mb1 = tid >> 3;
    for (int mt = 0; mt < 13; ++mt) {
      int m0 = mt * 64;
      __syncthreads();
      *(int4*)&KVs[lr][lc] =
          (m0 + lr < kN) ? *(const int4*)&kb[(size_t)(m0 + lr) * kD + lc] : z4;
      __syncthreads();
#pragma unroll
      for (int j = 0; j < 2; ++j) {
        int m = mb1 + (j << 5);
        int acc = 0;
#pragma unroll
        for (int kk = 0; kk < 16; ++kk)
          acc = dot4i8(qreg[kk], *(const int*)&KVs[m][kk << 2], acc);
        double attnv = ((double)acc * s1s1) * 0.125;
        double aq = fmin(fmax(rint(attnv / s_a + dit), -128.0), 127.0);
        AQ[r1][m0 + m] = (int8_t)(int)aq;
      }
    }
  }
  __syncthreads();

  // phase 2: integer int_softmax -> digit planes (values == r13's P4, exact)
  {
    int x0i = (int)x0;
    int wid = tid >> 6, lane = tid & 63;
    for (int rr = 0; rr < 2; ++rr) {
      int row = wid * 2 + rr;
      int rmax = -128;
      for (int m = lane; m < kN; m += 64) rmax = max(rmax, (int)AQ[row][m]);
      rmax = wave_max_i(rmax);
      long long sd = 0;
      for (int m = lane; m < kN; m += 64)
        sd += p_eval((int)AQ[row][m] - rmax, x0i);
      for (int off = 32; off; off >>= 1) sd += __shfl_xor(sd, off);
      long long S = sd > 2147483647LL ? 2147483647LL : sd;
      long long SLo = S + kDS;
      long long SHi = S - kDS; if (SHi < 1) SHi = 1;
      if (SLo > 2147483647LL) SLo = 2147483647LL;
      // operands fit u32: identical quotients, much cheaper than i64 soft-div
      long long fLo = (long long)(2147483647u / (unsigned)SLo);
      long long fHi = (long long)(2147483647u / (unsigned)SHi);
      for (int m = lane; m < kN; m += 64) {
        int p4 = p4_final((long long)p_eval((int)AQ[row][m] - rmax, x0i), fLo, fHi);
        int b0 = (int)(int8_t)(p4 & 0xff);
        int t1 = (p4 - b0) >> 8;          // exact
        int b1 = (int)(int8_t)(t1 & 0xff);
        int b2 = (t1 - b1) >> 8;          // in [0,3]
        PL[0][row][m] = (int8_t)b0;
        PL[1][row][m] = (int8_t)b1;
        PL[2][row][m] = (int8_t)b2;
      }
      for (int m = kN + lane; m < 832; m += 64) {
        PL[0][row][m] = 0; PL[1][row][m] = 0; PL[2][row][m] = 0;
      }
    }
  }
  __syncthreads();

  // phase 3: MFMA PV — per wave one 16-d subtile; accumulate over all m.
  {
    int w = tid >> 6, l = tid & 63;
    int frow = (l & 15) & 7;
    int fk = (l >> 4) << 4;
    int dglob = w * 16 + (l & 15);
    const int8_t* vtb = vT8 + ((size_t)bh * kD + dglob) * kNp;
    i32x4 a0, a1, a2;
    a0[0]=0;a0[1]=0;a0[2]=0;a0[3]=0;
    a1[0]=0;a1[1]=0;a1[2]=0;a1[3]=0;
    a2[0]=0;a2[1]=0;a2[2]=0;a2[3]=0;
    for (int mt = 0; mt < 13; ++mt) {
      int m0 = mt * 64;
      i32x4 bf = *(const i32x4*)&vtb[m0 + fk];
      i32x4 f0 = *(const i32x4*)&PL[0][frow][m0 + fk];
      i32x4 f1 = *(const i32x4*)&PL[1][frow][m0 + fk];
      i32x4 f2 = *(const i32x4*)&PL[2][frow][m0 + fk];
      mfma_i8_acc(a0, f0, bf);
      mfma_i8_acc(a1, f1, bf);
      mfma_i8_acc(a2, f2, bf);
    }
    double mymax = 0.0;
    int qhi = l >> 4;
#pragma unroll
    for (int r = 0; r < 4; ++r) {
      int q = qhi * 4 + r;
      if (q < 8) {
        long long tot = (long long)a0[r] + ((long long)a1[r] << 8) +
                        ((long long)a2[r] << 16);
        double v = 0.25 * (double)tot;
        pv[((size_t)bb * kN + (n0 + q)) * kC + hh * kD + dglob] = (float)v;
        mymax = fmax(mymax, fabs(v));
      }
    }
    mymax = wave_max_d(mymax);
    __shared__ double sredd[4];
    if (l == 0) sredd[w] = mymax;
    __syncthreads();
    if (tid == 0) {
      double mm = fmax(fmax(sredd[0], sredd[1]), fmax(sredd[2], sredd[3]));
      atomicMax((unsigned long long*)(ctl + 24),
                (unsigned long long)__double_as_longlong(mm));
    }
  }
}

// ---------------- quantize attn output per branch (dithered) ----------------
__global__ __launch_bounds__(256) void k_quant_o(
    const float* __restrict__ pv, const char* __restrict__ ctl,
    int8_t* __restrict__ o8, double dit) {
  double c2 = get_c2(ctl);
  double s_o = get_so(ctl);
  int total = kM * kC;
  for (int i = blockIdx.x * 256 + threadIdx.x; i < total; i += gridDim.x * 256) {
    double arg = ((double)pv[i] * c2) / s_o;
    double v = fmin(fmax(rint(arg + dit), -128.0), 127.0);
    o8[i] = (int8_t)(int)v;
  }
}

// ---------------- proj bias + max per branch (shared pmax atomic) ----------------
__global__ __launch_bounds__(256) void k_bias_max(
    int* __restrict__ p2, const double* __restrict__ wsp,
    const float* __restrict__ bias, char* __restrict__ ctl, double dit) {
  double s_o = get_so(ctl);
  int n = blockIdx.x;
  int* rowp = p2 + (size_t)n * kC;
  double m = 0.0;
  for (int o = threadIdx.x; o < kC; o += 256) {
    double outs = wsp[o] * s_o;
    double bint = rint((double)bias[o] / outs + dit);
    int a = rowp[o] + (int)bint;
    rowp[o] = a;
    m = fmax(m, fabs((double)a * outs));
  }
  m = wave_max_d(m);
  __shared__ double sred[4];
  if ((threadIdx.x & 63) == 0) sred[threadIdx.x >> 6] = m;
  __syncthreads();
  if (threadIdx.x == 0) {
    double mm = fmax(fmax(sred[0], sred[1]), fmax(sred[2], sred[3]));
    atomicMax((unsigned long long*)(ctl + 16),
              (unsigned long long)__double_as_longlong(mm));
  }
}

// ---------------- final: branch midpoint ----------------
__global__ __launch_bounds__(256) void k_final(
    const int* __restrict__ p2A, const int* __restrict__ p2B,
    const double* __restrict__ wsp,
    const char* __restrict__ ctl, float* __restrict__ out) {
  double s_o = get_so(ctl);
  double s_out = ctl_pmax(ctl) / 32767.0;
  int total = kM * kC;
  for (int i = blockIdx.x * 256 + threadIdx.x; i < total; i += gridDim.x * 256) {
    int o = i % kC;
    double outs = wsp[o] * s_o;
    double vA = fmin(fmax(rint(((double)p2A[i] * outs) / s_out - kEps), -32768.0), 32767.0);
    double vB = fmin(fmax(rint(((double)p2B[i] * outs) / s_out + kEps), -32768.0), 32767.0);
    out[i] = (float)(0.5 * (vA + vB) * s_out);
  }
  if (blockIdx.x == 0 && threadIdx.x == 0) out[total] = (float)s_out;
}

}  // namespace

extern "C" void kernel_launch(void* const* d_in, const int* in_sizes, int n_in,
                              void* d_out, int out_size, void* d_ws, size_t ws_size,
                              hipStream_t stream) {
  const float* x   = (const float*)d_in[0];
  const float* sin = (const float*)d_in[1];
  const float* Wq  = (const float*)d_in[2];
  const float* Wp  = (const float*)d_in[3];
  const float* bp  = (const float*)d_in[4];
  float* out = (float*)d_out;

  char* ws = (char*)d_ws;
  char* ctl = ws;
  size_t off = 1024;
  int8_t* x8   = (int8_t*)(ws + off); off += (size_t)kM * kC;
  int8_t* wq8A = (int8_t*)(ws + off); off += (size_t)kOC * kC;
  int8_t* wq8B = (int8_t*)(ws + off); off += (size_t)kOC * kC;
  int8_t* wp8A = (int8_t*)(ws + off); off += (size_t)kC * kC;
  int8_t* wp8B = (int8_t*)(ws + off); off += (size_t)kC * kC;
  off = (off + 255) & ~(size_t)255;
  double* outs_q = (double*)(ws + off); off += (size_t)kOC * 8;
  double* wsp    = (double*)(ws + off); off += (size_t)kC * 8;
  off = (off + 255) & ~(size_t)255;
  int8_t* qkvA = (int8_t*)(ws + off); off += 3 * SZ_QKV1;
  int8_t* qkvB = (int8_t*)(ws + off); off += 3 * SZ_QKV1;
  int8_t* qA = qkvA, *kA = qkvA + SZ_QKV1;
  int8_t* qB = qkvB, *kB = qkvB + SZ_QKV1;
  off = (off + 255) & ~(size_t)255;
  int8_t* vT8A = (int8_t*)(ws + off); off += SZ_VT;
  int8_t* vT8B = (int8_t*)(ws + off); off += SZ_VT;
  int8_t* o8A = (int8_t*)(ws + off); off += (size_t)kM * kC;
  int8_t* o8B = (int8_t*)(ws + off); off += (size_t)kM * kC;
  off = (off + 255) & ~(size_t)255;
  float* pvA = (float*)(ws + off); int* p2A = (int*)pvA; off += (size_t)kM * kC * 4;
  float* pvB = (float*)(ws + off); int* p2B = (int*)pvB; off += (size_t)kM * kC * 4;

  dim3 g1(kOC / 128, kM / 128);
  hipMemsetAsync(ctl, 0, 1024, stream);
  k_quant_w<<<kOC + kC, 256, 0, stream>>>(Wq, Wp, sin, wq8A, wq8B, wp8A, wp8B,
                                          outs_q, wsp);
  k_quant_x<<<2048, 256, 0, stream>>>(x, sin, x8);
  k_gemm1m<0><<<g1, 256, 0, stream>>>(x8, wq8A, outs_q, ctl, nullptr, nullptr, 0.0);
  k_gemm1m<0><<<g1, 256, 0, stream>>>(x8, wq8B, outs_q, ctl, nullptr, nullptr, 0.0);
  k_gemm1m<1><<<g1, 256, 0, stream>>>(x8, wq8A, outs_q, ctl, qkvA, vT8A, -kEps);
  k_gemm1m<1><<<g1, 256, 0, stream>>>(x8, wq8B, outs_q, ctl, qkvB, vT8B, +kEps);
  k_qkmaxm<<<dim3(13, 13, kBH), 256, 0, stream>>>(qA, kA, ctl);
  k_qkmaxm<<<dim3(13, 13, kBH), 256, 0, stream>>>(qB, kB, ctl);
  k_attn<<<dim3(98, kBH), 256, 0, stream>>>(qA, kA, vT8A, ctl, pvA, -kEps, -kEpsX0);
  k_attn<<<dim3(98, kBH), 256, 0, stream>>>(qB, kB, vT8B, ctl, pvB, +kEps, +kEpsX0);
  k_quant_o<<<2048, 256, 0, stream>>>(pvA, ctl, o8A, -kEps);
  k_quant_o<<<2048, 256, 0, stream>>>(pvB, ctl, o8B, +kEps);
  k_gemm_i8m<<<dim3(kC / 128, kM / 128), 256, 0, stream>>>(o8A, wp8A, p2A, kC, kC);
  k_gemm_i8m<<<dim3(kC / 128, kM / 128), 256, 0, stream>>>(o8B, wp8B, p2B, kC, kC);
  k_bias_max<<<kM, 256, 0, stream>>>(p2A, wsp, bp, ctl, -kEps);
  k_bias_max<<<kM, 256, 0, stream>>>(p2B, wsp, bp, ctl, +kEps);
  k_final<<<2048, 256, 0, stream>>>(p2A, p2B, wsp, ctl, out);
}

// Round 18
// 1104.173 us; speedup vs baseline: 2.4299x; 1.2167x over previous
//
#include <hip/hip_runtime.h>
#include <cstdint>
#include <cstddef>

#define DEV __device__ __forceinline__

namespace {

constexpr int kN = 784, kC = 768, kH = 12, kD = 64;
constexpr int kM = 6272, kOC = 2304, kBH = 96;
constexpr int kNp = 832;                 // padded row length for V^T
constexpr size_t SZ_QKV1 = (size_t)kBH * kN * kD;
constexpr size_t SZ_VT   = (size_t)kBH * kD * kNp;
constexpr double kEps   = 2.0e-3;        // activation-round dither
constexpr double kEpsW  = 3.0e-5;        // weight-round dither
constexpr double kEpsX0 = 3.0e-5;        // x0 floor dither
constexpr long long kDS = 1024;          // np-f32 exp_sum ambiguity band
constexpr long long kEP = 128;           // np-f32 (p*factor) product ulp band
constexpr double kGuard = 1.0e-9;        // mul-vs-div boundary guard

using i32x4 = __attribute__((ext_vector_type(4))) int;

DEV void mfma_i8_acc(i32x4& c, i32x4 a, i32x4 b) {
  c = __builtin_amdgcn_mfma_i32_16x16x64_i8(a, b, c, 0, 0, 0);
}

DEV double wave_max_d(double v) {
  for (int o = 32; o; o >>= 1) v = fmax(v, __shfl_xor(v, o));
  return v;
}
DEV int wave_max_i(int v) {
  for (int o = 32; o; o >>= 1) v = max(v, __shfl_xor(v, o));
  return v;
}

// ctl: [0] u64 dbl max|h| ; [8] int max|qk| ; [16] u64 dbl max|proj| ;
// [24] u64 dbl max|pv|
DEV double ctl_hmax(const char* c)  { return __longlong_as_double(*(const long long*)(c)); }
DEV int    ctl_qkmax(const char* c) { return *(const int*)(c + 8); }
DEV double ctl_pmax(const char* c)  { return __longlong_as_double(*(const long long*)(c + 16)); }
DEV double ctl_pvmax(const char* c) { return __longlong_as_double(*(const long long*)(c + 24)); }

DEV double get_s1(const char* c) { return ctl_hmax(c) / 127.0; }
DEV double get_sa(const char* c) {
  double s1 = get_s1(c);
  double amax = ((double)ctl_qkmax(c) * (s1 * s1)) * 0.125;
  return amax / 127.0;
}
DEV double get_c2(const char* c) { return get_s1(c) * 3.0517578125e-05; }
DEV double get_so(const char* c) { return (ctl_pvmax(c) * get_c2(c)) / 127.0; }

// shift-exp of int_softmax, exact integer form. xi <= 0, x0i < 0.
DEV int p_eval(int xi, int x0i) {
  int x2 = xi + (xi >> 1) - (xi >> 4);
  x2 = max(x2, 15 * x0i);
  int q = x2 / x0i;
  int rrem = x2 - x0i * q;
  int base = rrem - 2 * x0i;
  return (q <= 14) ? (base << (14 - q)) : (base >> 1);
}

// Integer 4*P version of r12's p_final — bit-identical values.
DEV int p4_final(long long p, long long fLo, long long fHi) {
  long long a = (p * fLo - kEP) >> 16;
  long long b = (p * fLo + kEP) >> 16;
  if (fLo == fHi) return (int)((a + b) << 1);
  long long c = (p * fHi - kEP) >> 16;
  long long d = (p * fHi + kEP) >> 16;
  return (int)(a + b + c + d);
}

// ---------------- weight quantization: shared scale, dithered A/B ints ----------------
__global__ __launch_bounds__(256) void k_quant_w(
    const float* __restrict__ Wq, const float* __restrict__ Wp,
    const float* __restrict__ s_in_p,
    int8_t* __restrict__ wq8A, int8_t* __restrict__ wq8B,
    int8_t* __restrict__ wp8A, int8_t* __restrict__ wp8B,
    double* __restrict__ outs_q, double* __restrict__ wsp) {
  int r = blockIdx.x;
  bool isq = r < kOC;
  const float* row = isq ? Wq + (size_t)r * kC : Wp + (size_t)(r - kOC) * kC;
  double m = 0.0;
  for (int i = threadIdx.x; i < kC; i += 256) m = fmax(m, fabs((double)row[i]));
  m = wave_max_d(m);
  __shared__ double sred[4];
  __shared__ double s_ws;
  if ((threadIdx.x & 63) == 0) sred[threadIdx.x >> 6] = m;
  __syncthreads();
  if (threadIdx.x == 0) {
    double mm = fmax(fmax(sred[0], sred[1]), fmax(sred[2], sred[3]));
    double ws = mm / 127.0;
    s_ws = ws;
    if (isq) outs_q[r] = ws * (double)s_in_p[0];
    else     wsp[r - kOC] = ws;
  }
  __syncthreads();
  double ws = s_ws;
  int8_t* dA = isq ? wq8A + (size_t)r * kC : wp8A + (size_t)(r - kOC) * kC;
  int8_t* dB = isq ? wq8B + (size_t)r * kC : wp8B + (size_t)(r - kOC) * kC;
  for (int i = threadIdx.x; i < kC; i += 256) {
    double arg = (double)row[i] / ws;
    dA[i] = (int8_t)(int)fmin(fmax(rint(arg - kEpsW), -128.0), 127.0);
    dB[i] = (int8_t)(int)fmin(fmax(rint(arg + kEpsW), -128.0), 127.0);
  }
}

// ---------------- x quantization (exact, shared) ----------------
__global__ __launch_bounds__(256) void k_quant_x(
    const float* __restrict__ x, const float* __restrict__ s_in_p,
    int8_t* __restrict__ x8) {
  double s = (double)s_in_p[0];
  int total = kM * kC;
  for (int i = blockIdx.x * 256 + threadIdx.x; i < total; i += gridDim.x * 256)
    x8[i] = (int8_t)(int)rint((double)x[i] / s);
}

// ------------- 128x128-tile MFMA GEMM1 per branch: MODE 0 hmax, MODE 1 quantize -------------
template <int MODE>
__global__ __launch_bounds__(256) void k_gemm1m(
    const int8_t* __restrict__ A, const int8_t* __restrict__ Bm,
    const double* __restrict__ outs_q, char* __restrict__ ctl,
    int8_t* __restrict__ qkv8, int8_t* __restrict__ vT8, double dit) {
  __shared__ __align__(16) int8_t As[128][80];
  __shared__ __align__(16) int8_t Bs[128][80];
  int bm = blockIdx.y * 128, bn = blockIdx.x * 128;
  int tid = threadIdx.x;
  int w = tid >> 6, l = tid & 63;
  int frow = l & 15, fk = (l >> 4) << 4;
  int rb = w * 32;
  i32x4 acc[2][8];
#pragma unroll
  for (int i = 0; i < 2; ++i)
#pragma unroll
    for (int s = 0; s < 8; ++s) { acc[i][s][0]=0; acc[i][s][1]=0; acc[i][s][2]=0; acc[i][s][3]=0; }
  for (int k0 = 0; k0 < kC; k0 += 64) {
    __syncthreads();
#pragma unroll
    for (int e = 0; e < 2; ++e) {
      int idx = tid + e * 256;
      int row = idx >> 2, cg = (idx & 3) << 4;
      *(int4*)&As[row][cg] = *(const int4*)&A[(size_t)(bm + row) * kC + k0 + cg];
      *(int4*)&Bs[row][cg] = *(const int4*)&Bm[(size_t)(bn + row) * kC + k0 + cg];
    }
    __syncthreads();
    i32x4 af0 = *(const i32x4*)&As[rb + frow][fk];
    i32x4 af1 = *(const i32x4*)&As[rb + 16 + frow][fk];
#pragma unroll
    for (int s = 0; s < 8; ++s) {
      i32x4 bf = *(const i32x4*)&Bs[s * 16 + frow][fk];
      mfma_i8_acc(acc[0][s], af0, bf);
      mfma_i8_acc(acc[1][s], af1, bf);
    }
  }
  if (MODE == 0) {
    double m = 0.0;
#pragma unroll
    for (int s = 0; s < 8; ++s) {
      double oq = outs_q[bn + s * 16 + frow];
#pragma unroll
      for (int i = 0; i < 2; ++i)
#pragma unroll
        for (int r = 0; r < 4; ++r)
          m = fmax(m, fabs((double)acc[i][s][r] * oq));
    }
    m = wave_max_d(m);
    __shared__ double sred[4];
    if (l == 0) sred[w] = m;
    __syncthreads();
    if (tid == 0) {
      double mm = fmax(fmax(sred[0], sred[1]), fmax(sred[2], sred[3]));
      atomicMax((unsigned long long*)ctl,
                (unsigned long long)__double_as_longlong(mm));
    }
  } else {
    double s1 = get_s1(ctl);
    double inv_s1 = 1.0 / s1;
#pragma unroll
    for (int s = 0; s < 8; ++s) {
      int o = bn + s * 16 + frow;
      double oq = outs_q[o];
      int which = o / kC, rem = o % kC;
      int hh = rem >> 6, dd = rem & 63;
#pragma unroll
      for (int i = 0; i < 2; ++i)
#pragma unroll
        for (int r = 0; r < 4; ++r) {
          int n = bm + rb + i * 16 + ((l >> 4) << 2) + r;
          double num = (double)acc[i][s][r] * oq;
          double t = num * inv_s1 + dit;             // fast path
          double r0 = rint(t);
          if (0.5 - fabs(t - r0) < kGuard) {          // boundary: exact fallback
            t = num / s1 + dit;
            r0 = rint(t);
          }
          double v = fmin(fmax(r0, -128.0), 127.0);
          int bb = n / kN, nn = n % kN;
          int8_t q8v = (int8_t)(int)v;
          qkv8[(size_t)which * SZ_QKV1 + (((size_t)bb * kH + hh) * kN + nn) * kD + dd] = q8v;
          if (which == 2)
            vT8[((size_t)(bb * kH + hh) * kD + dd) * kNp + nn] = q8v;
        }
    }
  }
}

// ---------------- 128x128 MFMA proj GEMM (exact int32) ----------------
__global__ __launch_bounds__(256) void k_gemm_i8m(
    const int8_t* __restrict__ A, const int8_t* __restrict__ Bm,
    int* __restrict__ Cout, int Ncols, int K) {
  __shared__ __align__(16) int8_t As[128][80];
  __shared__ __align__(16) int8_t Bs[128][80];
  int bm = blockIdx.y * 128, bn = blockIdx.x * 128;
  int tid = threadIdx.x;
  int w = tid >> 6, l = tid & 63;
  int frow = l & 15, fk = (l >> 4) << 4;
  int rb = w * 32;
  i32x4 acc[2][8];
#pragma unroll
  for (int i = 0; i < 2; ++i)
#pragma unroll
    for (int s = 0; s < 8; ++s) { acc[i][s][0]=0; acc[i][s][1]=0; acc[i][s][2]=0; acc[i][s][3]=0; }
  for (int k0 = 0; k0 < K; k0 += 64) {
    __syncthreads();
#pragma unroll
    for (int e = 0; e < 2; ++e) {
      int idx = tid + e * 256;
      int row = idx >> 2, cg = (idx & 3) << 4;
      *(int4*)&As[row][cg] = *(const int4*)&A[(size_t)(bm + row) * K + k0 + cg];
      *(int4*)&Bs[row][cg] = *(const int4*)&Bm[(size_t)(bn + row) * K + k0 + cg];
    }
    __syncthreads();
    i32x4 af0 = *(const i32x4*)&As[rb + frow][fk];
    i32x4 af1 = *(const i32x4*)&As[rb + 16 + frow][fk];
#pragma unroll
    for (int s = 0; s < 8; ++s) {
      i32x4 bf = *(const i32x4*)&Bs[s * 16 + frow][fk];
      mfma_i8_acc(acc[0][s], af0, bf);
      mfma_i8_acc(acc[1][s], af1, bf);
    }
  }
#pragma unroll
  for (int s = 0; s < 8; ++s) {
    int n = bn + s * 16 + frow;
#pragma unroll
    for (int i = 0; i < 2; ++i)
#pragma unroll
      for (int r = 0; r < 4; ++r) {
        int m = bm + rb + i * 16 + ((l >> 4) << 2) + r;
        Cout[(size_t)m * Ncols + n] = acc[i][s][r];
      }
  }
}

// ---------------- MFMA global max |q.k| (int exact; per branch) ----------------
__global__ __launch_bounds__(256) void k_qkmaxm(
    const int8_t* __restrict__ q8, const int8_t* __restrict__ k8,
    char* __restrict__ ctl) {
  __shared__ __align__(16) int8_t As[64][80];
  __shared__ __align__(16) int8_t Bs[64][80];
  int bh = blockIdx.z;
  int n0 = blockIdx.y * 64, m0 = blockIdx.x * 64;
  const int8_t* qb = q8 + (size_t)bh * kN * kD;
  const int8_t* kb = k8 + (size_t)bh * kN * kD;
  int tid = threadIdx.x;
  int lrow = tid >> 2, lcol = (tid & 3) << 4;
  int w = tid >> 6, l = tid & 63;
  int frow = l & 15, fk = (l >> 4) << 4;
  int4 z4 = make_int4(0, 0, 0, 0);
  *(int4*)&As[lrow][lcol] =
      (n0 + lrow < kN) ? *(const int4*)&qb[(size_t)(n0 + lrow) * kD + lcol] : z4;
  *(int4*)&Bs[lrow][lcol] =
      (m0 + lrow < kN) ? *(const int4*)&kb[(size_t)(m0 + lrow) * kD + lcol] : z4;
  __syncthreads();
  i32x4 acc[4];
#pragma unroll
  for (int s = 0; s < 4; ++s) { acc[s][0] = 0; acc[s][1] = 0; acc[s][2] = 0; acc[s][3] = 0; }
  i32x4 af = *(const i32x4*)&As[w * 16 + frow][fk];
#pragma unroll
  for (int s = 0; s < 4; ++s) {
    i32x4 bf = *(const i32x4*)&Bs[s * 16 + frow][fk];
    mfma_i8_acc(acc[s], af, bf);
  }
  int mx = 0;
#pragma unroll
  for (int s = 0; s < 4; ++s)
#pragma unroll
    for (int r = 0; r < 4; ++r) mx = max(mx, abs(acc[s][r]));
  mx = wave_max_i(mx);
  __shared__ int sred[4];
  if (l == 0) sred[w] = mx;
  __syncthreads();
  if (tid == 0) {
    int mm = max(max(sred[0], sred[1]), max(sred[2], sred[3]));
    atomicMax((int*)(ctl + 8), mm);
  }
}

// --- fused attn per branch (QBLK=16): MFMA QK^T + int softmax + MFMA PV ---
// AQ aliased onto PL[0] (dead after parr fill). All quant expressions bit-exact
// to r12 via guarded reciprocal-mul with exact-division fallback.
__global__ __launch_bounds__(256) void k_attn(
    const int8_t* __restrict__ q8, const int8_t* __restrict__ k8,
    const int8_t* __restrict__ vT8, char* __restrict__ ctl,
    float* __restrict__ pv, double dit, double x0dit) {
  double s1 = get_s1(ctl);
  double s1s1 = s1 * s1;
  double s_a = get_sa(ctl);
  double inv_sa = 1.0 / s_a;
  double x0 = floor(-1.0 / s_a + x0dit);

  int bh = blockIdx.y;
  int n0 = blockIdx.x * 16;
  int bb = bh / kH, hh = bh % kH;
  const int8_t* kb = k8 + (size_t)bh * kN * kD;

  __shared__ __align__(16) int8_t Qs[16][64];
  __shared__ __align__(16) int8_t PL[3][16][848];   // PL[0] doubles as AQ

  int tid = threadIdx.x;
  int w = tid >> 6, l = tid & 63;

  // load Q tile (16 rows x 64B)
  {
    int row = tid >> 4, c4 = (tid & 15) << 2;
    *(int*)&Qs[row][c4] =
        *(const int*)&q8[((size_t)bh * kN + n0 + row) * kD + c4];
  }
  __syncthreads();

  // phase 1: MFMA QK^T (one k-step, D=64) -> quantized attn ints into PL[0]
  {
    int frow = l & 15, fk = (l >> 4) << 4;
    i32x4 af = *(const i32x4*)&Qs[frow][fk];
    for (int t = w; t < 49; t += 4) {
      int m0 = t * 16;
      i32x4 bf = *(const i32x4*)&kb[(size_t)(m0 + frow) * kD + fk];
      i32x4 c; c[0] = 0; c[1] = 0; c[2] = 0; c[3] = 0;
      mfma_i8_acc(c, af, bf);
#pragma unroll
      for (int r = 0; r < 4; ++r) {
        int q = ((l >> 4) << 2) + r;
        double attnv = ((double)c[r] * s1s1) * 0.125;
        double t_f = attnv * inv_sa + dit;           // fast path
        double r0 = rint(t_f);
        if (0.5 - fabs(t_f - r0) < kGuard) {          // boundary: exact fallback
          double t_e = attnv / s_a + dit;
          r0 = rint(t_e);
        }
        double aq = fmin(fmax(r0, -128.0), 127.0);
        PL[0][q][m0 + frow] = (int8_t)(int)aq;
      }
    }
  }
  __syncthreads();

  // phase 2: integer int_softmax -> digit planes (p_eval cached in registers)
  {
    int x0i = (int)x0;
    int lane = l;
    for (int rr = 0; rr < 4; ++rr) {
      int row = w * 4 + rr;
      int rmax = -128;
#pragma unroll
      for (int i = 0; i < 13; ++i) {
        int m = lane + i * 64;
        if (m < kN) rmax = max(rmax, (int)(int8_t)PL[0][row][m]);
      }
      rmax = wave_max_i(rmax);
      int parr[13];
      long long sd = 0;
#pragma unroll
      for (int i = 0; i < 13; ++i) {
        int m = lane + i * 64;
        int p = 0;
        if (m < kN) { p = p_eval((int)(int8_t)PL[0][row][m] - rmax, x0i); sd += p; }
        parr[i] = p;
      }
      for (int off = 32; off; off >>= 1) sd += __shfl_xor(sd, off);
      long long S = sd > 2147483647LL ? 2147483647LL : sd;
      long long SLo = S + kDS;
      long long SHi = S - kDS; if (SHi < 1) SHi = 1;
      if (SLo > 2147483647LL) SLo = 2147483647LL;
      long long fLo = (long long)(2147483647u / (unsigned)SLo);
      long long fHi = (long long)(2147483647u / (unsigned)SHi);
#pragma unroll
      for (int i = 0; i < 13; ++i) {
        int m = lane + i * 64;
        if (m < kN) {
          int p4 = p4_final((long long)parr[i], fLo, fHi);
          int b0 = (int)(int8_t)(p4 & 0xff);
          int t1 = (p4 - b0) >> 8;
          int b1 = (int)(int8_t)(t1 & 0xff);
          int b2 = (t1 - b1) >> 8;
          PL[0][row][m] = (int8_t)b0;
          PL[1][row][m] = (int8_t)b1;
          PL[2][row][m] = (int8_t)b2;
        }
      }
      for (int m = kN + lane; m < 832; m += 64) {
        PL[0][row][m] = 0; PL[1][row][m] = 0; PL[2][row][m] = 0;
      }
    }
  }
  __syncthreads();

  // phase 3: MFMA PV — per wave one 16-d subtile; 16 valid q rows.
  {
    int frow = l & 15;
    int fk = (l >> 4) << 4;
    int dglob = w * 16 + frow;
    const int8_t* vtb = vT8 + ((size_t)bh * kD + dglob) * kNp;
    i32x4 a0, a1, a2;
    a0[0]=0;a0[1]=0;a0[2]=0;a0[3]=0;
    a1[0]=0;a1[1]=0;a1[2]=0;a1[3]=0;
    a2[0]=0;a2[1]=0;a2[2]=0;a2[3]=0;
    for (int mt = 0; mt < 13; ++mt) {
      int m0 = mt * 64;
      i32x4 bf = *(const i32x4*)&vtb[m0 + fk];
      i32x4 f0 = *(const i32x4*)&PL[0][frow][m0 + fk];
      i32x4 f1 = *(const i32x4*)&PL[1][frow][m0 + fk];
      i32x4 f2 = *(const i32x4*)&PL[2][frow][m0 + fk];
      mfma_i8_acc(a0, f0, bf);
      mfma_i8_acc(a1, f1, bf);
      mfma_i8_acc(a2, f2, bf);
    }
    double mymax = 0.0;
    int qhi = l >> 4;
#pragma unroll
    for (int r = 0; r < 4; ++r) {
      int q = qhi * 4 + r;
      long long tot = (long long)a0[r] + ((long long)a1[r] << 8) +
                      ((long long)a2[r] << 16);
      double v = 0.25 * (double)tot;
      pv[((size_t)bb * kN + (n0 + q)) * kC + hh * kD + dglob] = (float)v;
      mymax = fmax(mymax, fabs(v));
    }
    mymax = wave_max_d(mymax);
    __shared__ double sredd[4];
    if (l == 0) sredd[w] = mymax;
    __syncthreads();
    if (tid == 0) {
      double mm = fmax(fmax(sredd[0], sredd[1]), fmax(sredd[2], sredd[3]));
      atomicMax((unsigned long long*)(ctl + 24),
                (unsigned long long)__double_as_longlong(mm));
    }
  }
}

// ---------------- per-column precompute: outs, bint (A and B) ----------------
__global__ __launch_bounds__(256) void k_prep(
    const double* __restrict__ wsp, const float* __restrict__ bias,
    const char* __restrict__ ctl, double* __restrict__ outsv,
    double* __restrict__ bintA, double* __restrict__ bintB) {
  double s_o = get_so(ctl);
  int o = blockIdx.x * 256 + threadIdx.x;
  if (o < kC) {
    double outs = wsp[o] * s_o;
    outsv[o] = outs;
    double base = (double)bias[o] / outs;
    bintA[o] = rint(base - kEps);
    bintB[o] = rint(base + kEps);
  }
}

// ---------------- quantize attn output per branch (dithered) ----------------
__global__ __launch_bounds__(256) void k_quant_o(
    const float* __restrict__ pv, const char* __restrict__ ctl,
    int8_t* __restrict__ o8, double dit) {
  double c2 = get_c2(ctl);
  double s_o = get_so(ctl);
  int total = kM * kC;
  for (int i = blockIdx.x * 256 + threadIdx.x; i < total; i += gridDim.x * 256) {
    double arg = ((double)pv[i] * c2) / s_o;
    double v = fmin(fmax(rint(arg + dit), -128.0), 127.0);
    o8[i] = (int8_t)(int)v;
  }
}

// ---------------- proj bias + max per branch (precomputed bint/outs) ----------------
__global__ __launch_bounds__(256) void k_bias_max(
    int* __restrict__ p2, const double* __restrict__ outsv,
    const double* __restrict__ bint, char* __restrict__ ctl) {
  int n = blockIdx.x;
  int* rowp = p2 + (size_t)n * kC;
  double m = 0.0;
  for (int o = threadIdx.x; o < kC; o += 256) {
    int a = rowp[o] + (int)bint[o];
    rowp[o] = a;
    m = fmax(m, fabs((double)a * outsv[o]));
  }
  m = wave_max_d(m);
  __shared__ double sred[4];
  if ((threadIdx.x & 63) == 0) sred[threadIdx.x >> 6] = m;
  __syncthreads();
  if (threadIdx.x == 0) {
    double mm = fmax(fmax(sred[0], sred[1]), fmax(sred[2], sred[3]));
    atomicMax((unsigned long long*)(ctl + 16),
              (unsigned long long)__double_as_longlong(mm));
  }
}

// ---------------- final: branch midpoint ----------------
__global__ __launch_bounds__(256) void k_final(
    const int* __restrict__ p2A, const int* __restrict__ p2B,
    const double* __restrict__ outsv,
    const char* __restrict__ ctl, float* __restrict__ out) {
  double s_out = ctl_pmax(ctl) / 32767.0;
  int total = kM * kC;
  for (int i = blockIdx.x * 256 + threadIdx.x; i < total; i += gridDim.x * 256) {
    int o = i % kC;
    double outs = outsv[o];
    double vA = fmin(fmax(rint(((double)p2A[i] * outs) / s_out - kEps), -32768.0), 32767.0);
    double vB = fmin(fmax(rint(((double)p2B[i] * outs) / s_out + kEps), -32768.0), 32767.0);
    out[i] = (float)(0.5 * (vA + vB) * s_out);
  }
  if (blockIdx.x == 0 && threadIdx.x == 0) out[total] = (float)s_out;
}

}  // namespace

extern "C" void kernel_launch(void* const* d_in, const int* in_sizes, int n_in,
                              void* d_out, int out_size, void* d_ws, size_t ws_size,
                              hipStream_t stream) {
  const float* x   = (const float*)d_in[0];
  const float* sin = (const float*)d_in[1];
  const float* Wq  = (const float*)d_in[2];
  const float* Wp  = (const float*)d_in[3];
  const float* bp  = (const float*)d_in[4];
  float* out = (float*)d_out;

  char* ws = (char*)d_ws;
  char* ctl = ws;
  size_t off = 1024;
  int8_t* x8   = (int8_t*)(ws + off); off += (size_t)kM * kC;
  int8_t* wq8A = (int8_t*)(ws + off); off += (size_t)kOC * kC;
  int8_t* wq8B = (int8_t*)(ws + off); off += (size_t)kOC * kC;
  int8_t* wp8A = (int8_t*)(ws + off); off += (size_t)kC * kC;
  int8_t* wp8B = (int8_t*)(ws + off); off += (size_t)kC * kC;
  off = (off + 255) & ~(size_t)255;
  double* outs_q = (double*)(ws + off); off += (size_t)kOC * 8;
  double* wsp    = (double*)(ws + off); off += (size_t)kC * 8;
  double* outsv  = (double*)(ws + off); off += (size_t)kC * 8;
  double* bintA  = (double*)(ws + off); off += (size_t)kC * 8;
  double* bintB  = (double*)(ws + off); off += (size_t)kC * 8;
  off = (off + 255) & ~(size_t)255;
  int8_t* qkvA = (int8_t*)(ws + off); off += 3 * SZ_QKV1;
  int8_t* qkvB = (int8_t*)(ws + off); off += 3 * SZ_QKV1;
  int8_t* qA = qkvA, *kA = qkvA + SZ_QKV1;
  int8_t* qB = qkvB, *kB = qkvB + SZ_QKV1;
  off = (off + 255) & ~(size_t)255;
  int8_t* vT8A = (int8_t*)(ws + off); off += SZ_VT;
  int8_t* vT8B = (int8_t*)(ws + off); off += SZ_VT;
  int8_t* o8A = (int8_t*)(ws + off); off += (size_t)kM * kC;
  int8_t* o8B = (int8_t*)(ws + off); off += (size_t)kM * kC;
  off = (off + 255) & ~(size_t)255;
  float* pvA = (float*)(ws + off); int* p2A = (int*)pvA; off += (size_t)kM * kC * 4;
  float* pvB = (float*)(ws + off); int* p2B = (int*)pvB; off += (size_t)kM * kC * 4;

  dim3 g1(kOC / 128, kM / 128);
  hipMemsetAsync(ctl, 0, 1024, stream);
  k_quant_w<<<kOC + kC, 256, 0, stream>>>(Wq, Wp, sin, wq8A, wq8B, wp8A, wp8B,
                                          outs_q, wsp);
  k_quant_x<<<2048, 256, 0, stream>>>(x, sin, x8);
  k_gemm1m<0><<<g1, 256, 0, stream>>>(x8, wq8A, outs_q, ctl, nullptr, nullptr, 0.0);
  k_gemm1m<0><<<g1, 256, 0, stream>>>(x8, wq8B, outs_q, ctl, nullptr, nullptr, 0.0);
  k_gemm1m<1><<<g1, 256, 0, stream>>>(x8, wq8A, outs_q, ctl, qkvA, vT8A, -kEps);
  k_gemm1m<1><<<g1, 256, 0, stream>>>(x8, wq8B, outs_q, ctl, qkvB, vT8B, +kEps);
  k_qkmaxm<<<dim3(13, 13, kBH), 256, 0, stream>>>(qA, kA, ctl);
  k_qkmaxm<<<dim3(13, 13, kBH), 256, 0, stream>>>(qB, kB, ctl);
  k_attn<<<dim3(49, kBH), 256, 0, stream>>>(qA, kA, vT8A, ctl, pvA, -kEps, -kEpsX0);
  k_attn<<<dim3(49, kBH), 256, 0, stream>>>(qB, kB, vT8B, ctl, pvB, +kEps, +kEpsX0);
  k_prep<<<3, 256, 0, stream>>>(wsp, bp, ctl, outsv, bintA, bintB);
  k_quant_o<<<2048, 256, 0, stream>>>(pvA, ctl, o8A, -kEps);
  k_quant_o<<<2048, 256, 0, stream>>>(pvB, ctl, o8B, +kEps);
  k_gemm_i8m<<<dim3(kC / 128, kM / 128), 256, 0, stream>>>(o8A, wp8A, p2A, kC, kC);
  k_gemm_i8m<<<dim3(kC / 128, kM / 128), 256, 0, stream>>>(o8B, wp8B, p2B, kC, kC);
  k_bias_max<<<kM, 256, 0, stream>>>(p2A, outsv, bintA, ctl);
  k_bias_max<<<kM, 256, 0, stream>>>(p2B, outsv, bintB, ctl);
  k_final<<<2048, 256, 0, stream>>>(p2A, p2B, outsv, ctl, out);
}

// Round 19
// 796.992 us; speedup vs baseline: 3.3664x; 1.3854x over previous
//
#include <hip/hip_runtime.h>
#include <cstdint>
#include <cstddef>

#define DEV __device__ __forceinline__

namespace {

constexpr int kN = 784, kC = 768, kH = 12, kD = 64;
constexpr int kM = 6272, kOC = 2304, kBH = 96;
constexpr int kNp = 832;                 // padded row length for V^T
constexpr size_t SZ_QKV1 = (size_t)kBH * kN * kD;
constexpr size_t SZ_VT   = (size_t)kBH * kD * kNp;
constexpr double kEps   = 2.0e-3;        // activation-round dither
constexpr double kEpsW  = 3.0e-5;        // weight-round dither
constexpr double kEpsX0 = 3.0e-5;        // x0 floor dither
constexpr long long kDS = 1024;          // np-f32 exp_sum ambiguity band
constexpr long long kEP = 128;           // np-f32 (p*factor) product ulp band
constexpr double kGuard = 1.0e-9;        // mul-vs-div boundary guard

using i32x4 = __attribute__((ext_vector_type(4))) int;

DEV void mfma_i8_acc(i32x4& c, i32x4 a, i32x4 b) {
  c = __builtin_amdgcn_mfma_i32_16x16x64_i8(a, b, c, 0, 0, 0);
}

DEV double wave_max_d(double v) {
  for (int o = 32; o; o >>= 1) v = fmax(v, __shfl_xor(v, o));
  return v;
}
DEV int wave_max_i(int v) {
  for (int o = 32; o; o >>= 1) v = max(v, __shfl_xor(v, o));
  return v;
}

// ctl: [0] u64 dbl max|h| ; [8] int max|qk| ; [16] u64 dbl max|proj| ;
// [24] u64 dbl max|pv|
DEV double ctl_hmax(const char* c)  { return __longlong_as_double(*(const long long*)(c)); }
DEV int    ctl_qkmax(const char* c) { return *(const int*)(c + 8); }
DEV double ctl_pmax(const char* c)  { return __longlong_as_double(*(const long long*)(c + 16)); }
DEV double ctl_pvmax(const char* c) { return __longlong_as_double(*(const long long*)(c + 24)); }

DEV double get_s1(const char* c) { return ctl_hmax(c) / 127.0; }
DEV double get_sa(const char* c) {
  double s1 = get_s1(c);
  double amax = ((double)ctl_qkmax(c) * (s1 * s1)) * 0.125;
  return amax / 127.0;
}
DEV double get_c2(const char* c) { return get_s1(c) * 3.0517578125e-05; }
DEV double get_so(const char* c) { return (ctl_pvmax(c) * get_c2(c)) / 127.0; }

// shift-exp of int_softmax, exact integer form. xi <= 0, x0i < 0.
DEV int p_eval(int xi, int x0i) {
  int x2 = xi + (xi >> 1) - (xi >> 4);
  x2 = max(x2, 15 * x0i);
  int q = x2 / x0i;
  int rrem = x2 - x0i * q;
  int base = rrem - 2 * x0i;
  return (q <= 14) ? (base << (14 - q)) : (base >> 1);
}

// Integer 4*P version of r12's p_final — bit-identical values.
DEV int p4_final(long long p, long long fLo, long long fHi) {
  long long a = (p * fLo - kEP) >> 16;
  long long b = (p * fLo + kEP) >> 16;
  if (fLo == fHi) return (int)((a + b) << 1);
  long long c = (p * fHi - kEP) >> 16;
  long long d = (p * fHi + kEP) >> 16;
  return (int)(a + b + c + d);
}

// ---------------- weight quantization: shared scale, dithered A/B ints ----------------
__global__ __launch_bounds__(256) void k_quant_w(
    const float* __restrict__ Wq, const float* __restrict__ Wp,
    const float* __restrict__ s_in_p,
    int8_t* __restrict__ wq8A, int8_t* __restrict__ wq8B,
    int8_t* __restrict__ wp8A, int8_t* __restrict__ wp8B,
    double* __restrict__ outs_q, double* __restrict__ wsp) {
  int r = blockIdx.x;
  bool isq = r < kOC;
  const float* row = isq ? Wq + (size_t)r * kC : Wp + (size_t)(r - kOC) * kC;
  double m = 0.0;
  for (int i = threadIdx.x; i < kC; i += 256) m = fmax(m, fabs((double)row[i]));
  m = wave_max_d(m);
  __shared__ double sred[4];
  __shared__ double s_ws;
  if ((threadIdx.x & 63) == 0) sred[threadIdx.x >> 6] = m;
  __syncthreads();
  if (threadIdx.x == 0) {
    double mm = fmax(fmax(sred[0], sred[1]), fmax(sred[2], sred[3]));
    double ws = mm / 127.0;
    s_ws = ws;
    if (isq) outs_q[r] = ws * (double)s_in_p[0];
    else     wsp[r - kOC] = ws;
  }
  __syncthreads();
  double ws = s_ws;
  int8_t* dA = isq ? wq8A + (size_t)r * kC : wp8A + (size_t)(r - kOC) * kC;
  int8_t* dB = isq ? wq8B + (size_t)r * kC : wp8B + (size_t)(r - kOC) * kC;
  for (int i = threadIdx.x; i < kC; i += 256) {
    double arg = (double)row[i] / ws;
    dA[i] = (int8_t)(int)fmin(fmax(rint(arg - kEpsW), -128.0), 127.0);
    dB[i] = (int8_t)(int)fmin(fmax(rint(arg + kEpsW), -128.0), 127.0);
  }
}

// ---------------- x quantization (exact, shared) ----------------
__global__ __launch_bounds__(256) void k_quant_x(
    const float* __restrict__ x, const float* __restrict__ s_in_p,
    int8_t* __restrict__ x8) {
  double s = (double)s_in_p[0];
  int total = kM * kC;
  for (int i = blockIdx.x * 256 + threadIdx.x; i < total; i += gridDim.x * 256)
    x8[i] = (int8_t)(int)rint((double)x[i] / s);
}

// ------------- 128x128-tile MFMA GEMM1 per branch: MODE 0 hmax, MODE 1 quantize -------------
template <int MODE>
__global__ __launch_bounds__(256) void k_gemm1m(
    const int8_t* __restrict__ A, const int8_t* __restrict__ Bm,
    const double* __restrict__ outs_q, char* __restrict__ ctl,
    int8_t* __restrict__ qkv8, int8_t* __restrict__ vT8, double dit) {
  __shared__ __align__(16) int8_t As[128][80];
  __shared__ __align__(16) int8_t Bs[128][80];
  int bm = blockIdx.y * 128, bn = blockIdx.x * 128;
  int tid = threadIdx.x;
  int w = tid >> 6, l = tid & 63;
  int frow = l & 15, fk = (l >> 4) << 4;
  int rb = w * 32;
  i32x4 acc[2][8];
#pragma unroll
  for (int i = 0; i < 2; ++i)
#pragma unroll
    for (int s = 0; s < 8; ++s) { acc[i][s][0]=0; acc[i][s][1]=0; acc[i][s][2]=0; acc[i][s][3]=0; }
  for (int k0 = 0; k0 < kC; k0 += 64) {
    __syncthreads();
#pragma unroll
    for (int e = 0; e < 2; ++e) {
      int idx = tid + e * 256;
      int row = idx >> 2, cg = (idx & 3) << 4;
      *(int4*)&As[row][cg] = *(const int4*)&A[(size_t)(bm + row) * kC + k0 + cg];
      *(int4*)&Bs[row][cg] = *(const int4*)&Bm[(size_t)(bn + row) * kC + k0 + cg];
    }
    __syncthreads();
    i32x4 af0 = *(const i32x4*)&As[rb + frow][fk];
    i32x4 af1 = *(const i32x4*)&As[rb + 16 + frow][fk];
#pragma unroll
    for (int s = 0; s < 8; ++s) {
      i32x4 bf = *(const i32x4*)&Bs[s * 16 + frow][fk];
      mfma_i8_acc(acc[0][s], af0, bf);
      mfma_i8_acc(acc[1][s], af1, bf);
    }
  }
  if (MODE == 0) {
    double m = 0.0;
#pragma unroll
    for (int s = 0; s < 8; ++s) {
      double oq = outs_q[bn + s * 16 + frow];
#pragma unroll
      for (int i = 0; i < 2; ++i)
#pragma unroll
        for (int r = 0; r < 4; ++r)
          m = fmax(m, fabs((double)acc[i][s][r] * oq));
    }
    m = wave_max_d(m);
    __shared__ double sred[4];
    if (l == 0) sred[w] = m;
    __syncthreads();
    if (tid == 0) {
      double mm = fmax(fmax(sred[0], sred[1]), fmax(sred[2], sred[3]));
      atomicMax((unsigned long long*)ctl,
                (unsigned long long)__double_as_longlong(mm));
    }
  } else {
    double s1 = get_s1(ctl);
    double inv_s1 = 1.0 / s1;
#pragma unroll
    for (int s = 0; s < 8; ++s) {
      int o = bn + s * 16 + frow;
      double oq = outs_q[o];
      int which = o / kC, rem = o % kC;
      int hh = rem >> 6, dd = rem & 63;
#pragma unroll
      for (int i = 0; i < 2; ++i)
#pragma unroll
        for (int r = 0; r < 4; ++r) {
          int n = bm + rb + i * 16 + ((l >> 4) << 2) + r;
          double num = (double)acc[i][s][r] * oq;
          double t = num * inv_s1 + dit;             // fast path
          double r0 = rint(t);
          if (0.5 - fabs(t - r0) < kGuard) {          // boundary: exact fallback
            t = num / s1 + dit;
            r0 = rint(t);
          }
          double v = fmin(fmax(r0, -128.0), 127.0);
          int bb = n / kN, nn = n % kN;
          int8_t q8v = (int8_t)(int)v;
          qkv8[(size_t)which * SZ_QKV1 + (((size_t)bb * kH + hh) * kN + nn) * kD + dd] = q8v;
          if (which == 2)
            vT8[((size_t)(bb * kH + hh) * kD + dd) * kNp + nn] = q8v;
        }
    }
  }
}

// ---------------- 128x128 MFMA proj GEMM (exact int32) ----------------
__global__ __launch_bounds__(256) void k_gemm_i8m(
    const int8_t* __restrict__ A, const int8_t* __restrict__ Bm,
    int* __restrict__ Cout, int Ncols, int K) {
  __shared__ __align__(16) int8_t As[128][80];
  __shared__ __align__(16) int8_t Bs[128][80];
  int bm = blockIdx.y * 128, bn = blockIdx.x * 128;
  int tid = threadIdx.x;
  int w = tid >> 6, l = tid & 63;
  int frow = l & 15, fk = (l >> 4) << 4;
  int rb = w * 32;
  i32x4 acc[2][8];
#pragma unroll
  for (int i = 0; i < 2; ++i)
#pragma unroll
    for (int s = 0; s < 8; ++s) { acc[i][s][0]=0; acc[i][s][1]=0; acc[i][s][2]=0; acc[i][s][3]=0; }
  for (int k0 = 0; k0 < K; k0 += 64) {
    __syncthreads();
#pragma unroll
    for (int e = 0; e < 2; ++e) {
      int idx = tid + e * 256;
      int row = idx >> 2, cg = (idx & 3) << 4;
      *(int4*)&As[row][cg] = *(const int4*)&A[(size_t)(bm + row) * K + k0 + cg];
      *(int4*)&Bs[row][cg] = *(const int4*)&Bm[(size_t)(bn + row) * K + k0 + cg];
    }
    __syncthreads();
    i32x4 af0 = *(const i32x4*)&As[rb + frow][fk];
    i32x4 af1 = *(const i32x4*)&As[rb + 16 + frow][fk];
#pragma unroll
    for (int s = 0; s < 8; ++s) {
      i32x4 bf = *(const i32x4*)&Bs[s * 16 + frow][fk];
      mfma_i8_acc(acc[0][s], af0, bf);
      mfma_i8_acc(acc[1][s], af1, bf);
    }
  }
#pragma unroll
  for (int s = 0; s < 8; ++s) {
    int n = bn + s * 16 + frow;
#pragma unroll
    for (int i = 0; i < 2; ++i)
#pragma unroll
      for (int r = 0; r < 4; ++r) {
        int m = bm + rb + i * 16 + ((l >> 4) << 2) + r;
        Cout[(size_t)m * Ncols + n] = acc[i][s][r];
      }
  }
}

// ------- global max |q.k| v2: one block per bh, K-plane in LDS (exact max) -------
__global__ __launch_bounds__(256) void k_qkmax2(
    const int8_t* __restrict__ qkv8, char* __restrict__ ctl) {
  int bh = blockIdx.x;
  const int8_t* qb = qkv8 + (size_t)bh * kN * kD;
  const int8_t* kb = qkv8 + SZ_QKV1 + (size_t)bh * kN * kD;
  __shared__ __align__(16) int8_t KS[784][80];
  int tid = threadIdx.x;
  for (int idx = tid; idx < 3136; idx += 256) {
    int row = idx >> 2, c16 = (idx & 3) << 4;
    *(int4*)&KS[row][c16] = *(const int4*)&kb[(size_t)row * kD + c16];
  }
  __syncthreads();
  int w = tid >> 6, l = tid & 63;
  int frow = l & 15, fk = (l >> 4) << 4;
  int mx = 0;
  for (int nt = w; nt < 49; nt += 4) {
    i32x4 af = *(const i32x4*)&qb[(size_t)(nt * 16 + frow) * kD + fk];
#pragma unroll 7
    for (int mt = 0; mt < 49; ++mt) {
      i32x4 bf = *(const i32x4*)&KS[mt * 16 + frow][fk];
      i32x4 c; c[0] = 0; c[1] = 0; c[2] = 0; c[3] = 0;
      mfma_i8_acc(c, af, bf);
      mx = max(mx, max(max(abs(c[0]), abs(c[1])), max(abs(c[2]), abs(c[3]))));
    }
  }
  mx = wave_max_i(mx);
  __shared__ int sred[4];
  if (l == 0) sred[w] = mx;
  __syncthreads();
  if (tid == 0) {
    int mm = max(max(sred[0], sred[1]), max(sred[2], sred[3]));
    atomicMax((int*)(ctl + 8), mm);
  }
}

// --- fused attn per branch (QBLK=16): MFMA QK^T + int softmax + MFMA PV ---
__global__ __launch_bounds__(256) void k_attn(
    const int8_t* __restrict__ q8, const int8_t* __restrict__ k8,
    const int8_t* __restrict__ vT8, char* __restrict__ ctl,
    float* __restrict__ pv, double dit, double x0dit) {
  double s1 = get_s1(ctl);
  double s1s1 = s1 * s1;
  double s_a = get_sa(ctl);
  double inv_sa = 1.0 / s_a;
  double x0 = floor(-1.0 / s_a + x0dit);

  int bh = blockIdx.y;
  int n0 = blockIdx.x * 16;
  int bb = bh / kH, hh = bh % kH;
  const int8_t* kb = k8 + (size_t)bh * kN * kD;

  __shared__ __align__(16) int8_t Qs[16][64];
  __shared__ __align__(16) int8_t PL[3][16][848];   // PL[0] doubles as AQ

  int tid = threadIdx.x;
  int w = tid >> 6, l = tid & 63;

  // load Q tile (16 rows x 64B)
  {
    int row = tid >> 4, c4 = (tid & 15) << 2;
    *(int*)&Qs[row][c4] =
        *(const int*)&q8[((size_t)bh * kN + n0 + row) * kD + c4];
  }
  __syncthreads();

  // phase 1: MFMA QK^T (one k-step, D=64) -> quantized attn ints into PL[0]
  {
    int frow = l & 15, fk = (l >> 4) << 4;
    i32x4 af = *(const i32x4*)&Qs[frow][fk];
    for (int t = w; t < 49; t += 4) {
      int m0 = t * 16;
      i32x4 bf = *(const i32x4*)&kb[(size_t)(m0 + frow) * kD + fk];
      i32x4 c; c[0] = 0; c[1] = 0; c[2] = 0; c[3] = 0;
      mfma_i8_acc(c, af, bf);
#pragma unroll
      for (int r = 0; r < 4; ++r) {
        int q = ((l >> 4) << 2) + r;
        double attnv = ((double)c[r] * s1s1) * 0.125;
        double t_f = attnv * inv_sa + dit;           // fast path
        double r0 = rint(t_f);
        if (0.5 - fabs(t_f - r0) < kGuard) {          // boundary: exact fallback
          double t_e = attnv / s_a + dit;
          r0 = rint(t_e);
        }
        double aq = fmin(fmax(r0, -128.0), 127.0);
        PL[0][q][m0 + frow] = (int8_t)(int)aq;
      }
    }
  }
  __syncthreads();

  // phase 2: integer int_softmax -> digit planes (p_eval cached in registers)
  {
    int x0i = (int)x0;
    int lane = l;
    for (int rr = 0; rr < 4; ++rr) {
      int row = w * 4 + rr;
      int rmax = -128;
#pragma unroll
      for (int i = 0; i < 13; ++i) {
        int m = lane + i * 64;
        if (m < kN) rmax = max(rmax, (int)(int8_t)PL[0][row][m]);
      }
      rmax = wave_max_i(rmax);
      int parr[13];
      long long sd = 0;
#pragma unroll
      for (int i = 0; i < 13; ++i) {
        int m = lane + i * 64;
        int p = 0;
        if (m < kN) { p = p_eval((int)(int8_t)PL[0][row][m] - rmax, x0i); sd += p; }
        parr[i] = p;
      }
      for (int off = 32; off; off >>= 1) sd += __shfl_xor(sd, off);
      long long S = sd > 2147483647LL ? 2147483647LL : sd;
      long long SLo = S + kDS;
      long long SHi = S - kDS; if (SHi < 1) SHi = 1;
      if (SLo > 2147483647LL) SLo = 2147483647LL;
      long long fLo = (long long)(2147483647u / (unsigned)SLo);
      long long fHi = (long long)(2147483647u / (unsigned)SHi);
#pragma unroll
      for (int i = 0; i < 13; ++i) {
        int m = lane + i * 64;
        if (m < kN) {
          int p4 = p4_final((long long)parr[i], fLo, fHi);
          int b0 = (int)(int8_t)(p4 & 0xff);
          int t1 = (p4 - b0) >> 8;
          int b1 = (int)(int8_t)(t1 & 0xff);
          int b2 = (t1 - b1) >> 8;
          PL[0][row][m] = (int8_t)b0;
          PL[1][row][m] = (int8_t)b1;
          PL[2][row][m] = (int8_t)b2;
        }
      }
      for (int m = kN + lane; m < 832; m += 64) {
        PL[0][row][m] = 0; PL[1][row][m] = 0; PL[2][row][m] = 0;
      }
    }
  }
  __syncthreads();

  // phase 3: MFMA PV — per wave one 16-d subtile; 16 valid q rows.
  {
    int frow = l & 15;
    int fk = (l >> 4) << 4;
    int dglob = w * 16 + frow;
    const int8_t* vtb = vT8 + ((size_t)bh * kD + dglob) * kNp;
    i32x4 a0, a1, a2;
    a0[0]=0;a0[1]=0;a0[2]=0;a0[3]=0;
    a1[0]=0;a1[1]=0;a1[2]=0;a1[3]=0;
    a2[0]=0;a2[1]=0;a2[2]=0;a2[3]=0;
    for (int mt = 0; mt < 13; ++mt) {
      int m0 = mt * 64;
      i32x4 bf = *(const i32x4*)&vtb[m0 + fk];
      i32x4 f0 = *(const i32x4*)&PL[0][frow][m0 + fk];
      i32x4 f1 = *(const i32x4*)&PL[1][frow][m0 + fk];
      i32x4 f2 = *(const i32x4*)&PL[2][frow][m0 + fk];
      mfma_i8_acc(a0, f0, bf);
      mfma_i8_acc(a1, f1, bf);
      mfma_i8_acc(a2, f2, bf);
    }
    double mymax = 0.0;
    int qhi = l >> 4;
#pragma unroll
    for (int r = 0; r < 4; ++r) {
      int q = qhi * 4 + r;
      long long tot = (long long)a0[r] + ((long long)a1[r] << 8) +
                      ((long long)a2[r] << 16);
      double v = 0.25 * (double)tot;
      pv[((size_t)bb * kN + (n0 + q)) * kC + hh * kD + dglob] = (float)v;
      mymax = fmax(mymax, fabs(v));
    }
    mymax = wave_max_d(mymax);
    __shared__ double sredd[4];
    if (l == 0) sredd[w] = mymax;
    __syncthreads();
    if (tid == 0) {
      double mm = fmax(fmax(sredd[0], sredd[1]), fmax(sredd[2], sredd[3]));
      atomicMax((unsigned long long*)(ctl + 24),
                (unsigned long long)__double_as_longlong(mm));
    }
  }
}

// ---------------- per-column precompute: outs, bint (A and B) ----------------
__global__ __launch_bounds__(256) void k_prep(
    const double* __restrict__ wsp, const float* __restrict__ bias,
    const char* __restrict__ ctl, double* __restrict__ outsv,
    double* __restrict__ bintA, double* __restrict__ bintB) {
  double s_o = get_so(ctl);
  int o = blockIdx.x * 256 + threadIdx.x;
  if (o < kC) {
    double outs = wsp[o] * s_o;
    outsv[o] = outs;
    double base = (double)bias[o] / outs;
    bintA[o] = rint(base - kEps);
    bintB[o] = rint(base + kEps);
  }
}

// ---------------- quantize attn output per branch (dithered) ----------------
__global__ __launch_bounds__(256) void k_quant_o(
    const float* __restrict__ pv, const char* __restrict__ ctl,
    int8_t* __restrict__ o8, double dit) {
  double c2 = get_c2(ctl);
  double s_o = get_so(ctl);
  int total = kM * kC;
  for (int i = blockIdx.x * 256 + threadIdx.x; i < total; i += gridDim.x * 256) {
    double arg = ((double)pv[i] * c2) / s_o;
    double v = fmin(fmax(rint(arg + dit), -128.0), 127.0);
    o8[i] = (int8_t)(int)v;
  }
}

// ---------------- proj bias + max per branch (precomputed bint/outs) ----------------
__global__ __launch_bounds__(256) void k_bias_max(
    int* __restrict__ p2, const double* __restrict__ outsv,
    const double* __restrict__ bint, char* __restrict__ ctl) {
  int n = blockIdx.x;
  int* rowp = p2 + (size_t)n * kC;
  double m = 0.0;
  for (int o = threadIdx.x; o < kC; o += 256) {
    int a = rowp[o] + (int)bint[o];
    rowp[o] = a;
    m = fmax(m, fabs((double)a * outsv[o]));
  }
  m = wave_max_d(m);
  __shared__ double sred[4];
  if ((threadIdx.x & 63) == 0) sred[threadIdx.x >> 6] = m;
  __syncthreads();
  if (threadIdx.x == 0) {
    double mm = fmax(fmax(sred[0], sred[1]), fmax(sred[2], sred[3]));
    atomicMax((unsigned long long*)(ctl + 16),
              (unsigned long long)__double_as_longlong(mm));
  }
}

// ---------------- final: branch midpoint ----------------
__global__ __launch_bounds__(256) void k_final(
    const int* __restrict__ p2A, const int* __restrict__ p2B,
    const double* __restrict__ outsv,
    const char* __restrict__ ctl, float* __restrict__ out) {
  double s_out = ctl_pmax(ctl) / 32767.0;
  int total = kM * kC;
  for (int i = blockIdx.x * 256 + threadIdx.x; i < total; i += gridDim.x * 256) {
    int o = i % kC;
    double outs = outsv[o];
    double vA = fmin(fmax(rint(((double)p2A[i] * outs) / s_out - kEps), -32768.0), 32767.0);
    double vB = fmin(fmax(rint(((double)p2B[i] * outs) / s_out + kEps), -32768.0), 32767.0);
    out[i] = (float)(0.5 * (vA + vB) * s_out);
  }
  if (blockIdx.x == 0 && threadIdx.x == 0) out[total] = (float)s_out;
}

}  // namespace

extern "C" void kernel_launch(void* const* d_in, const int* in_sizes, int n_in,
                              void* d_out, int out_size, void* d_ws, size_t ws_size,
                              hipStream_t stream) {
  const float* x   = (const float*)d_in[0];
  const float* sin = (const float*)d_in[1];
  const float* Wq  = (const float*)d_in[2];
  const float* Wp  = (const float*)d_in[3];
  const float* bp  = (const float*)d_in[4];
  float* out = (float*)d_out;

  char* ws = (char*)d_ws;
  char* ctl = ws;
  size_t off = 1024;
  int8_t* x8   = (int8_t*)(ws + off); off += (size_t)kM * kC;
  int8_t* wq8A = (int8_t*)(ws + off); off += (size_t)kOC * kC;
  int8_t* wq8B = (int8_t*)(ws + off); off += (size_t)kOC * kC;
  int8_t* wp8A = (int8_t*)(ws + off); off += (size_t)kC * kC;
  int8_t* wp8B = (int8_t*)(ws + off); off += (size_t)kC * kC;
  off = (off + 255) & ~(size_t)255;
  double* outs_q = (double*)(ws + off); off += (size_t)kOC * 8;
  double* wsp    = (double*)(ws + off); off += (size_t)kC * 8;
  double* outsv  = (double*)(ws + off); off += (size_t)kC * 8;
  double* bintA  = (double*)(ws + off); off += (size_t)kC * 8;
  double* bintB  = (double*)(ws + off); off += (size_t)kC * 8;
  off = (off + 255) & ~(size_t)255;
  int8_t* qkvA = (int8_t*)(ws + off); off += 3 * SZ_QKV1;
  int8_t* qkvB = (int8_t*)(ws + off); off += 3 * SZ_QKV1;
  int8_t* qA = qkvA, *kA = qkvA + SZ_QKV1;
  int8_t* qB = qkvB, *kB = qkvB + SZ_QKV1;
  off = (off + 255) & ~(size_t)255;
  int8_t* vT8A = (int8_t*)(ws + off); off += SZ_VT;
  int8_t* vT8B = (int8_t*)(ws + off); off += SZ_VT;
  int8_t* o8A = (int8_t*)(ws + off); off += (size_t)kM * kC;
  int8_t* o8B = (int8_t*)(ws + off); off += (size_t)kM * kC;
  off = (off + 255) & ~(size_t)255;
  float* pvA = (float*)(ws + off); int* p2A = (int*)pvA; off += (size_t)kM * kC * 4;
  float* pvB = (float*)(ws + off); int* p2B = (int*)pvB; off += (size_t)kM * kC * 4;

  dim3 g1(kOC / 128, kM / 128);
  hipMemsetAsync(ctl, 0, 1024, stream);
  k_quant_w<<<kOC + kC, 256, 0, stream>>>(Wq, Wp, sin, wq8A, wq8B, wp8A, wp8B,
                                          outs_q, wsp);
  k_quant_x<<<2048, 256, 0, stream>>>(x, sin, x8);
  k_gemm1m<0><<<g1, 256, 0, stream>>>(x8, wq8A, outs_q, ctl, nullptr, nullptr, 0.0);
  k_gemm1m<0><<<g1, 256, 0, stream>>>(x8, wq8B, outs_q, ctl, nullptr, nullptr, 0.0);
  k_gemm1m<1><<<g1, 256, 0, stream>>>(x8, wq8A, outs_q, ctl, qkvA, vT8A, -kEps);
  k_gemm1m<1><<<g1, 256, 0, stream>>>(x8, wq8B, outs_q, ctl, qkvB, vT8B, +kEps);
  k_qkmax2<<<kBH, 256, 0, stream>>>(qkvA, ctl);
  k_qkmax2<<<kBH, 256, 0, stream>>>(qkvB, ctl);
  k_attn<<<dim3(49, kBH), 256, 0, stream>>>(qA, kA, vT8A, ctl, pvA, -kEps, -kEpsX0);
  k_attn<<<dim3(49, kBH), 256, 0, stream>>>(qB, kB, vT8B, ctl, pvB, +kEps, +kEpsX0);
  k_prep<<<3, 256, 0, stream>>>(wsp, bp, ctl, outsv, bintA, bintB);
  k_quant_o<<<2048, 256, 0, stream>>>(pvA, ctl, o8A, -kEps);
  k_quant_o<<<2048, 256, 0, stream>>>(pvB, ctl, o8B, +kEps);
  k_gemm_i8m<<<dim3(kC / 128, kM / 128), 256, 0, stream>>>(o8A, wp8A, p2A, kC, kC);
  k_gemm_i8m<<<dim3(kC / 128, kM / 128), 256, 0, stream>>>(o8B, wp8B, p2B, kC, kC);
  k_bias_max<<<kM, 256, 0, stream>>>(p2A, outsv, bintA, ctl);
  k_bias_max<<<kM, 256, 0, stream>>>(p2B, outsv, bintB, ctl);
  k_final<<<2048, 256, 0, stream>>>(p2A, p2B, outsv, ctl, out);
}